// Round 4
// baseline (634.586 us; speedup 1.0000x reference)
//
#include <hip/hip_runtime.h>
#include <hip/hip_bf16.h>
#include <stdint.h>

// Harness contract: reference is pure fp32 => all d_in are float*, d_out is
// float*. We convert to bf16 internally for MFMA, accumulate fp32.

typedef __attribute__((ext_vector_type(8))) short short8;   // 8 bf16 = 4 VGPRs (MFMA A/B frag)
typedef __attribute__((ext_vector_type(4))) short short4v;  // 4 bf16 = 8B
typedef __attribute__((ext_vector_type(4))) float floatx4;  // MFMA C/D frag

#define DEV static __device__ __forceinline__

DEV float b2f(short s) {
    unsigned u = ((unsigned)(unsigned short)s) << 16;
    return __uint_as_float(u);
}
DEV short f2b(float f) {  // round-to-nearest-even bf16
    unsigned u = __float_as_uint(f);
    u += 0x7fffu + ((u >> 16) & 1u);
    return (short)(u >> 16);
}

// async global->LDS, 16B per lane; HW writes lane i at wavebase + i*16
// (pass per-lane LDS ptr = base + lane*16 so source layout matches HW).
typedef const __attribute__((address_space(1))) unsigned gu32;
typedef __attribute__((address_space(3))) unsigned lu32;
DEV void g2l16(const void* g, void* l) {
    __builtin_amdgcn_global_load_lds((gu32*)(uintptr_t)g,
                                     (lu32*)(unsigned)(uintptr_t)l, 16, 0, 0);
}

// ---------------------------------------------------------------------------
// LayerNorm: y = gamma*(x-mean)/(std+eps)+beta, std = sqrt(sum((x-m)^2)/(n-1))
// fp32 in, bf16 out. one row (1024) per block of 256 threads
// ---------------------------------------------------------------------------
__global__ __launch_bounds__(256) void ln_kernel(const float* __restrict__ x,
                                                 const float* __restrict__ gamma,
                                                 const float* __restrict__ beta,
                                                 short* __restrict__ y) {
    int row = blockIdx.x;
    int t = threadIdx.x;
    float4 v = *(const float4*)(x + (size_t)row * 1024 + t * 4);
    float f[4] = {v.x, v.y, v.z, v.w};
    float s = 0.f, ss = 0.f;
#pragma unroll
    for (int i = 0; i < 4; i++) { s += f[i]; ss += f[i] * f[i]; }
#pragma unroll
    for (int off = 32; off; off >>= 1) { s += __shfl_xor(s, off); ss += __shfl_xor(ss, off); }
    __shared__ float rs[4], rss[4];
    int wid = t >> 6, lane = t & 63;
    if (lane == 0) { rs[wid] = s; rss[wid] = ss; }
    __syncthreads();
    s = rs[0] + rs[1] + rs[2] + rs[3];
    ss = rss[0] + rss[1] + rss[2] + rss[3];
    float mean = s * (1.0f / 1024.0f);
    float var = (ss - 1024.0f * mean * mean) * (1.0f / 1023.0f);
    var = fmaxf(var, 0.0f);
    float inv = 1.0f / (sqrtf(var) + 1e-5f);
    float4 g = *(const float4*)(gamma + t * 4);
    float4 bb = *(const float4*)(beta + t * 4);
    short4v o;
    o[0] = f2b(g.x * (f[0] - mean) * inv + bb.x);
    o[1] = f2b(g.y * (f[1] - mean) * inv + bb.y);
    o[2] = f2b(g.z * (f[2] - mean) * inv + bb.z);
    o[3] = f2b(g.w * (f[3] - mean) * inv + bb.w);
    *(short4v*)(y + (size_t)row * 1024 + t * 4) = o;
}

// ---------------------------------------------------------------------------
// Weight transpose + fp32->bf16: out[c*R + r] = bf16(in[r*C + c])
// ---------------------------------------------------------------------------
__global__ __launch_bounds__(256) void transpose_w(const float* __restrict__ in,
                                                   short* __restrict__ out,
                                                   int R, int C) {
    __shared__ short tile[32][33];
    int tx = threadIdx.x & 31, ty = threadIdx.x >> 5;
    int c0 = blockIdx.x * 32, r0 = blockIdx.y * 32;
#pragma unroll
    for (int i = 0; i < 4; i++)
        tile[ty + i * 8][tx] = f2b(in[(size_t)(r0 + ty + i * 8) * C + c0 + tx]);
    __syncthreads();
#pragma unroll
    for (int i = 0; i < 4; i++)
        out[(size_t)(c0 + ty + i * 8) * R + r0 + tx] = tile[tx][ty + i * 8];
}

// ---------------------------------------------------------------------------
// V^T prep: vt[bh][d][key] = qkv[b*2048+key][2048 + h*64 + d]  (bf16->bf16)
// grid: (64 key-tiles, 2 dim-tiles, 64 bh)
// ---------------------------------------------------------------------------
__global__ __launch_bounds__(256) void vtprep_kernel(const short* __restrict__ qkv,
                                                     short* __restrict__ vt) {
    __shared__ short tile[32][33];
    int tx = threadIdx.x & 31, ty = threadIdx.x >> 5;
    int bh = blockIdx.z, b = bh >> 4, h = bh & 15;
    int k0 = blockIdx.x * 32, d0 = blockIdx.y * 32;
#pragma unroll
    for (int i = 0; i < 4; i++)
        tile[ty + i * 8][tx] =
            qkv[(size_t)(b * 2048 + k0 + ty + i * 8) * 3072 + 2048 + h * 64 + d0 + tx];
    __syncthreads();
#pragma unroll
    for (int i = 0; i < 4; i++)
        vt[(size_t)bh * 131072 + (size_t)(d0 + ty + i * 8) * 2048 + k0 + tx] =
            tile[tx][ty + i * 8];
}

// ---------------------------------------------------------------------------
// GEMM: C[M,N] = A[M,K](bf16) * Bt[N,K]^T(bf16) (+bias fp32) (relu) (+res fp32)
// m97 structure: global_load_lds width=16 into unpadded LDS [128][32],
// XOR chunk swizzle (c ^= (row>>1)&3) so b128 frag reads are ~2-way.
// block 256 = 4 waves (2x2), tile 128x128, BK=32, mfma 16x16x32 bf16
// ---------------------------------------------------------------------------
template <int RELU, int OUTF32>
__global__ __launch_bounds__(256) void gemm_bt(const short* __restrict__ A,
                                               const short* __restrict__ Bt,
                                               const float* __restrict__ bias,
                                               const float* __restrict__ res,
                                               void* __restrict__ Cout,
                                               int M, int N, int K) {
    __shared__ short lA[128 * 32];
    __shared__ short lB[128 * 32];
    int t = threadIdx.x;
    int bn = blockIdx.x, bm = blockIdx.y;
    int w = t >> 6, lane = t & 63, quad = lane >> 4, l15 = lane & 15;
    int wm = (w >> 1) * 64, wn = (w & 1) * 64;
    floatx4 acc[4][4] = {};
    const int nkt = K >> 5;
    int S0 = w * 64 + lane, S1 = 256 + S0;
    int r0 = S0 >> 2, c0 = (S0 & 3) ^ ((r0 >> 1) & 3);
    int r1 = S1 >> 2, c1 = (S1 & 3) ^ ((r1 >> 1) & 3);
    const short* Ag0 = A + (size_t)(bm * 128 + r0) * K + c0 * 8;
    const short* Ag1 = A + (size_t)(bm * 128 + r1) * K + c1 * 8;
    const short* Bg0 = Bt + (size_t)(bn * 128 + r0) * K + c0 * 8;
    const short* Bg1 = Bt + (size_t)(bn * 128 + r1) * K + c1 * 8;
    short* lA0 = &lA[S0 * 8]; short* lA1 = &lA[S1 * 8];
    short* lB0 = &lB[S0 * 8]; short* lB1 = &lB[S1 * 8];
    for (int kt = 0; kt < nkt; kt++) {
        g2l16(Ag0 + kt * 32, lA0);
        g2l16(Ag1 + kt * 32, lA1);
        g2l16(Bg0 + kt * 32, lB0);
        g2l16(Bg1 + kt * 32, lB1);
        __syncthreads();   // drains vmcnt(0): staged data visible
        short8 af[4], bf[4];
#pragma unroll
        for (int mt = 0; mt < 4; mt++) {
            int row = wm + mt * 16 + l15;
            int c = quad ^ ((row >> 1) & 3);
            af[mt] = *(short8*)&lA[row * 32 + c * 8];
        }
#pragma unroll
        for (int nt = 0; nt < 4; nt++) {
            int row = wn + nt * 16 + l15;
            int c = quad ^ ((row >> 1) & 3);
            bf[nt] = *(short8*)&lB[row * 32 + c * 8];
        }
#pragma unroll
        for (int mt = 0; mt < 4; mt++)
#pragma unroll
            for (int nt = 0; nt < 4; nt++)
                acc[mt][nt] = __builtin_amdgcn_mfma_f32_16x16x32_bf16(
                    af[mt], bf[nt], acc[mt][nt], 0, 0, 0);
        __syncthreads();
    }
#pragma unroll
    for (int mt = 0; mt < 4; mt++) {
#pragma unroll
        for (int nt = 0; nt < 4; nt++) {
            int col = bn * 128 + wn + nt * 16 + l15;
            float bv = bias ? bias[col] : 0.0f;
#pragma unroll
            for (int r = 0; r < 4; r++) {
                int row = bm * 128 + wm + mt * 16 + quad * 4 + r;
                float v = acc[mt][nt][r] + bv;
                if (RELU) v = fmaxf(v, 0.0f);
                if (res) v += res[(size_t)row * N + col];
                if (OUTF32)
                    ((float*)Cout)[(size_t)row * N + col] = v;
                else
                    ((short*)Cout)[(size_t)row * N + col] = f2b(v);
            }
        }
    }
}

// ---------------------------------------------------------------------------
// N-narrow GEMM for the K-deep, N=1024 cases (Wout, FF2), fp32 out + bias +
// fp32 residual. Tile 128(M)x64(N), BK=32 -> grid (N/64, M/128) = 1024 blocks
// = 4 blocks/CU (fixes the 2-blocks/CU occupancy wall seen at 128x128).
// 4 waves (2m x 2n), wave tile 64x32: 8 MFMA/iter. 3 g2l16/lane/iter.
// ---------------------------------------------------------------------------
__global__ __launch_bounds__(256) void gemm_bt_n64(const short* __restrict__ A,
                                                   const short* __restrict__ Bt,
                                                   const float* __restrict__ bias,
                                                   const float* __restrict__ res,
                                                   float* __restrict__ Cout,
                                                   int M, int N, int K) {
    __shared__ short lA[128 * 32];   // 512 16B chunks
    __shared__ short lB[64 * 32];    // 256 16B chunks
    int t = threadIdx.x;
    int bn = blockIdx.x, bm = blockIdx.y;
    int w = t >> 6, lane = t & 63, quad = lane >> 4, l15 = lane & 15;
    int wm = (w >> 1) * 64, wn = (w & 1) * 32;
    floatx4 acc[4][2] = {};
    const int nkt = K >> 5;
    int S0 = w * 64 + lane, S1 = 256 + S0;
    int ra0 = S0 >> 2, ca0 = (S0 & 3) ^ ((ra0 >> 1) & 3);
    int ra1 = S1 >> 2, ca1 = (S1 & 3) ^ ((ra1 >> 1) & 3);
    int rb = S0 >> 2, cb = (S0 & 3) ^ ((rb >> 1) & 3);
    const short* Ag0 = A + (size_t)(bm * 128 + ra0) * K + ca0 * 8;
    const short* Ag1 = A + (size_t)(bm * 128 + ra1) * K + ca1 * 8;
    const short* Bg0 = Bt + (size_t)(bn * 64 + rb) * K + cb * 8;
    short* lA0 = &lA[S0 * 8]; short* lA1 = &lA[S1 * 8];
    short* lB0 = &lB[S0 * 8];
    for (int kt = 0; kt < nkt; kt++) {
        g2l16(Ag0 + kt * 32, lA0);
        g2l16(Ag1 + kt * 32, lA1);
        g2l16(Bg0 + kt * 32, lB0);
        __syncthreads();
        short8 af[4], bf[2];
#pragma unroll
        for (int mt = 0; mt < 4; mt++) {
            int row = wm + mt * 16 + l15;
            int c = quad ^ ((row >> 1) & 3);
            af[mt] = *(short8*)&lA[row * 32 + c * 8];
        }
#pragma unroll
        for (int nt = 0; nt < 2; nt++) {
            int row = wn + nt * 16 + l15;
            int c = quad ^ ((row >> 1) & 3);
            bf[nt] = *(short8*)&lB[row * 32 + c * 8];
        }
#pragma unroll
        for (int mt = 0; mt < 4; mt++)
#pragma unroll
            for (int nt = 0; nt < 2; nt++)
                acc[mt][nt] = __builtin_amdgcn_mfma_f32_16x16x32_bf16(
                    af[mt], bf[nt], acc[mt][nt], 0, 0, 0);
        __syncthreads();
    }
#pragma unroll
    for (int mt = 0; mt < 4; mt++) {
#pragma unroll
        for (int nt = 0; nt < 2; nt++) {
            int col = bn * 64 + wn + nt * 16 + l15;
            float bv = bias[col];
#pragma unroll
            for (int r = 0; r < 4; r++) {
                int row = bm * 128 + wm + mt * 16 + quad * 4 + r;
                Cout[(size_t)row * N + col] =
                    acc[mt][nt][r] + bv + res[(size_t)row * N + col];
            }
        }
    }
}

// ---------------------------------------------------------------------------
// Flash attention: grid (16 qtiles, 16 heads, 4 batch), block 256 = 4 waves
// each wave: 32 queries x 64 dims; K-tiles of 64 keys.
// No running max (|S/32| << 88). Q prescaled by 2^-5 (exact in bf16), so the
// softmax inner loop is just __expf + sum-add + v_perm truncation pack.
// lK rows key-permuted (row j holds key (j&15)*4+(j>>4)) -> P writes are one
// b64 per 4 contiguous k'. K/V staged via global_load_lds, XOR swizzle.
// ---------------------------------------------------------------------------
__global__ __launch_bounds__(256) void attn_kernel(const short* __restrict__ qkv,
                                                   const short* __restrict__ vt,
                                                   short* __restrict__ out) {
    __shared__ short lK[64 * 64];
    __shared__ short lV[64 * 64];
    __shared__ short lP[4 * 32 * 72];
    int t = threadIdx.x;
    int w = t >> 6, lane = t & 63, quad = lane >> 4, l15 = lane & 15;
    int qt = blockIdx.x, h = blockIdx.y, b = blockIdx.z;
    int qrow0 = b * 2048 + qt * 128 + w * 32;
    short* lPw = &lP[w * 32 * 72];

    // Q fragments, prescaled by SCALE = 2^-5 (exact in bf16)
    short8 qf[2][2];
#pragma unroll
    for (int mt = 0; mt < 2; mt++)
#pragma unroll
        for (int kc = 0; kc < 2; kc++) {
            short8 q = *(const short8*)(qkv + (size_t)(qrow0 + mt * 16 + l15) * 3072 +
                                        h * 64 + kc * 32 + quad * 8);
#pragma unroll
            for (int i = 0; i < 8; i++) q[i] = f2b(b2f(q[i]) * 0.03125f);
            qf[mt][kc] = q;
        }

    float l_s[2][4] = {};
    floatx4 o[2][4] = {};

    int S0 = w * 64 + lane, S1 = 256 + S0;
    int r0 = S0 >> 3, c0 = (S0 & 7) ^ (r0 & 7);
    int r1 = S1 >> 3, c1 = (S1 & 7) ^ (r1 & 7);
    int kr0 = (r0 & 15) * 4 + (r0 >> 4);
    int kr1 = (r1 & 15) * 4 + (r1 >> 4);
    const short* Kg0 = qkv + (size_t)(b * 2048 + kr0) * 3072 + 1024 + h * 64 + c0 * 8;
    const short* Kg1 = qkv + (size_t)(b * 2048 + kr1) * 3072 + 1024 + h * 64 + c1 * 8;
    const short* Vg0 = vt + (size_t)(b * 16 + h) * 131072 + (size_t)r0 * 2048 + c0 * 8;
    const short* Vg1 = vt + (size_t)(b * 16 + h) * 131072 + (size_t)r1 * 2048 + c1 * 8;
    short* lK0 = &lK[S0 * 8]; short* lK1 = &lK[S1 * 8];
    short* lV0 = &lV[S0 * 8]; short* lV1 = &lV[S1 * 8];

    for (int kt = 0; kt < 32; kt++) {
        __syncthreads();
        int key0 = kt * 64;
        g2l16(Kg0 + (size_t)key0 * 3072, lK0);
        g2l16(Kg1 + (size_t)key0 * 3072, lK1);
        g2l16(Vg0 + key0, lV0);
        g2l16(Vg1 + key0, lV1);
        __syncthreads();

        // S = (Q*2^-5) K^T   (col (nt,l15) is key k' = l15*4+nt)
        floatx4 s[2][4] = {};
#pragma unroll
        for (int kc = 0; kc < 2; kc++) {
            short8 kf[4];
#pragma unroll
            for (int nt = 0; nt < 4; nt++) {
                int row = nt * 16 + l15;
                int c = (kc * 4 + quad) ^ (row & 7);
                kf[nt] = *(short8*)&lK[row * 64 + c * 8];
            }
#pragma unroll
            for (int mt = 0; mt < 2; mt++)
#pragma unroll
                for (int nt = 0; nt < 4; nt++)
                    s[mt][nt] = __builtin_amdgcn_mfma_f32_16x16x32_bf16(
                        qf[mt][kc], kf[nt], s[mt][nt], 0, 0, 0);
        }

        // p = exp(S); lane-local partial row-sum; truncation-pack to bf16
#pragma unroll
        for (int mt = 0; mt < 2; mt++) {
#pragma unroll
            for (int r = 0; r < 4; r++) {
                float p0 = __expf(s[mt][0][r]);
                float p1 = __expf(s[mt][1][r]);
                float p2 = __expf(s[mt][2][r]);
                float p3 = __expf(s[mt][3][r]);
                l_s[mt][r] += (p0 + p1) + (p2 + p3);
                uint2 pk;
                pk.x = __builtin_amdgcn_perm(__float_as_uint(p1),
                                             __float_as_uint(p0), 0x07060302u);
                pk.y = __builtin_amdgcn_perm(__float_as_uint(p3),
                                             __float_as_uint(p2), 0x07060302u);
                *(uint2*)&lPw[(mt * 16 + quad * 4 + r) * 72 + l15 * 4] = pk;
            }
        }
        // lP is wave-private: no barrier needed

        // O += P V
#pragma unroll
        for (int kc = 0; kc < 2; kc++) {
            short8 pf[2], vf[4];
#pragma unroll
            for (int mt = 0; mt < 2; mt++)
                pf[mt] = *(short8*)&lPw[(mt * 16 + l15) * 72 + kc * 32 + quad * 8];
#pragma unroll
            for (int nt = 0; nt < 4; nt++) {
                int row = nt * 16 + l15;
                int c = (kc * 4 + quad) ^ (row & 7);
                vf[nt] = *(short8*)&lV[row * 64 + c * 8];
            }
#pragma unroll
            for (int mt = 0; mt < 2; mt++)
#pragma unroll
                for (int nt = 0; nt < 4; nt++)
                    o[mt][nt] = __builtin_amdgcn_mfma_f32_16x16x32_bf16(
                        pf[mt], vf[nt], o[mt][nt], 0, 0, 0);
        }
    }

#pragma unroll
    for (int mt = 0; mt < 2; mt++)
#pragma unroll
        for (int r = 0; r < 4; r++) {
            float v = l_s[mt][r];
            v += __shfl_xor(v, 1); v += __shfl_xor(v, 2);
            v += __shfl_xor(v, 4); v += __shfl_xor(v, 8);
            l_s[mt][r] = v;
        }

#pragma unroll
    for (int mt = 0; mt < 2; mt++)
#pragma unroll
        for (int nt = 0; nt < 4; nt++)
#pragma unroll
            for (int r = 0; r < 4; r++) {
                int row = qrow0 + mt * 16 + quad * 4 + r;
                int col = h * 64 + nt * 16 + l15;
                out[(size_t)row * 1024 + col] = f2b(o[mt][nt][r] / l_s[mt][r]);
            }
}

// ---------------------------------------------------------------------------
extern "C" void kernel_launch(void* const* d_in, const int* in_sizes, int n_in,
                              void* d_out, int out_size, void* d_ws, size_t ws_size,
                              hipStream_t stream) {
    const float* x      = (const float*)d_in[0];
    const float* w_qkv  = (const float*)d_in[1];
    const float* w_out  = (const float*)d_in[2];
    const float* b_out  = (const float*)d_in[3];
    const float* w1     = (const float*)d_in[4];
    const float* b1     = (const float*)d_in[5];
    const float* w2     = (const float*)d_in[6];
    const float* b2     = (const float*)d_in[7];
    const float* gamma1 = (const float*)d_in[8];
    const float* beta1  = (const float*)d_in[9];
    const float* gamma2 = (const float*)d_in[10];
    const float* beta2  = (const float*)d_in[11];
    float* out = (float*)d_out;

    // Workspace layout (byte offsets, 136MB high-water):
    //   0: wqkvT 6MB | 6: woutT 2MB | 8: w1T 8MB | 16: w2T 8MB
    //  24: h1 16MB (LN1 out -> attn out -> LN2 out)
    //  40: qkv 48MB + 88: vt 16MB  (both dead after attn; ff1 64MB spans both)
    // 104: x2 fp32 32MB (live to end)
    char* ws = (char*)d_ws;
    const size_t MB = 1024u * 1024u;
    short* wqkvT = (short*)(ws + 0 * MB);
    short* woutT = (short*)(ws + 6 * MB);
    short* w1T   = (short*)(ws + 8 * MB);
    short* w2T   = (short*)(ws + 16 * MB);
    short* h1    = (short*)(ws + 24 * MB);
    short* qkv   = (short*)(ws + 40 * MB);
    short* vt    = (short*)(ws + 88 * MB);
    short* ff1   = (short*)(ws + 40 * MB);
    float* x2    = (float*)(ws + 104 * MB);
    short* attn  = h1;   // h1 dead after QKV gemm
    short* h2    = h1;   // attn out dead after Wout gemm

    dim3 blk(256);
    transpose_w<<<dim3(96, 32), blk, 0, stream>>>(w_qkv, wqkvT, 1024, 3072);
    transpose_w<<<dim3(32, 32), blk, 0, stream>>>(w_out, woutT, 1024, 1024);
    transpose_w<<<dim3(128, 32), blk, 0, stream>>>(w1, w1T, 1024, 4096);
    transpose_w<<<dim3(32, 128), blk, 0, stream>>>(w2, w2T, 4096, 1024);

    ln_kernel<<<8192, blk, 0, stream>>>(x, gamma1, beta1, h1);
    gemm_bt<0, 0><<<dim3(24, 64), blk, 0, stream>>>(h1, wqkvT, nullptr, nullptr, qkv,
                                                    8192, 3072, 1024);
    vtprep_kernel<<<dim3(64, 2, 64), blk, 0, stream>>>(qkv, vt);
    attn_kernel<<<dim3(16, 16, 4), blk, 0, stream>>>(qkv, vt, attn);
    gemm_bt_n64<<<dim3(16, 64), blk, 0, stream>>>(attn, woutT, b_out, x, x2,
                                                  8192, 1024, 1024);
    ln_kernel<<<8192, blk, 0, stream>>>(x2, gamma2, beta2, h2);
    gemm_bt<1, 0><<<dim3(32, 64), blk, 0, stream>>>(h2, w1T, b1, nullptr, ff1,
                                                    8192, 4096, 1024);
    gemm_bt_n64<<<dim3(16, 64), blk, 0, stream>>>(ff1, w2T, b2, x2, out,
                                                  8192, 1024, 4096);
}

// Round 5
// 572.421 us; speedup vs baseline: 1.1086x; 1.1086x over previous
//
#include <hip/hip_runtime.h>
#include <hip/hip_bf16.h>
#include <stdint.h>

// Harness contract: reference is pure fp32 => all d_in are float*, d_out is
// float*. We convert to bf16 internally for MFMA, accumulate fp32.

typedef __attribute__((ext_vector_type(8))) short short8;   // 8 bf16 = 4 VGPRs (MFMA A/B frag)
typedef __attribute__((ext_vector_type(4))) short short4v;  // 4 bf16 = 8B
typedef __attribute__((ext_vector_type(4))) float floatx4;  // MFMA C/D frag

#define DEV static __device__ __forceinline__

DEV float b2f(short s) {
    unsigned u = ((unsigned)(unsigned short)s) << 16;
    return __uint_as_float(u);
}
DEV short f2b(float f) {  // round-to-nearest-even bf16
    unsigned u = __float_as_uint(f);
    u += 0x7fffu + ((u >> 16) & 1u);
    return (short)(u >> 16);
}

// async global->LDS, 16B per lane; HW writes lane i at wavebase + i*16
// (pass per-lane LDS ptr = base + lane*16 so source layout matches HW).
typedef const __attribute__((address_space(1))) unsigned gu32;
typedef __attribute__((address_space(3))) unsigned lu32;
DEV void g2l16(const void* g, void* l) {
    __builtin_amdgcn_global_load_lds((gu32*)(uintptr_t)g,
                                     (lu32*)(unsigned)(uintptr_t)l, 16, 0, 0);
}

// ---------------------------------------------------------------------------
// LayerNorm: y = gamma*(x-mean)/(std+eps)+beta, std = sqrt(sum((x-m)^2)/(n-1))
// fp32 in, bf16 out. one row (1024) per block of 256 threads
// ---------------------------------------------------------------------------
__global__ __launch_bounds__(256) void ln_kernel(const float* __restrict__ x,
                                                 const float* __restrict__ gamma,
                                                 const float* __restrict__ beta,
                                                 short* __restrict__ y) {
    int row = blockIdx.x;
    int t = threadIdx.x;
    float4 v = *(const float4*)(x + (size_t)row * 1024 + t * 4);
    float f[4] = {v.x, v.y, v.z, v.w};
    float s = 0.f, ss = 0.f;
#pragma unroll
    for (int i = 0; i < 4; i++) { s += f[i]; ss += f[i] * f[i]; }
#pragma unroll
    for (int off = 32; off; off >>= 1) { s += __shfl_xor(s, off); ss += __shfl_xor(ss, off); }
    __shared__ float rs[4], rss[4];
    int wid = t >> 6, lane = t & 63;
    if (lane == 0) { rs[wid] = s; rss[wid] = ss; }
    __syncthreads();
    s = rs[0] + rs[1] + rs[2] + rs[3];
    ss = rss[0] + rss[1] + rss[2] + rss[3];
    float mean = s * (1.0f / 1024.0f);
    float var = (ss - 1024.0f * mean * mean) * (1.0f / 1023.0f);
    var = fmaxf(var, 0.0f);
    float inv = 1.0f / (sqrtf(var) + 1e-5f);
    float4 g = *(const float4*)(gamma + t * 4);
    float4 bb = *(const float4*)(beta + t * 4);
    short4v o;
    o[0] = f2b(g.x * (f[0] - mean) * inv + bb.x);
    o[1] = f2b(g.y * (f[1] - mean) * inv + bb.y);
    o[2] = f2b(g.z * (f[2] - mean) * inv + bb.z);
    o[3] = f2b(g.w * (f[3] - mean) * inv + bb.w);
    *(short4v*)(y + (size_t)row * 1024 + t * 4) = o;
}

// ---------------------------------------------------------------------------
// Weight transpose + fp32->bf16: out[c*R + r] = bf16(in[r*C + c])
// ---------------------------------------------------------------------------
__global__ __launch_bounds__(256) void transpose_w(const float* __restrict__ in,
                                                   short* __restrict__ out,
                                                   int R, int C) {
    __shared__ short tile[32][33];
    int tx = threadIdx.x & 31, ty = threadIdx.x >> 5;
    int c0 = blockIdx.x * 32, r0 = blockIdx.y * 32;
#pragma unroll
    for (int i = 0; i < 4; i++)
        tile[ty + i * 8][tx] = f2b(in[(size_t)(r0 + ty + i * 8) * C + c0 + tx]);
    __syncthreads();
#pragma unroll
    for (int i = 0; i < 4; i++)
        out[(size_t)(c0 + ty + i * 8) * R + r0 + tx] = tile[tx][ty + i * 8];
}

// ---------------------------------------------------------------------------
// V^T prep: vt[bh][d][key] = qkv[b*2048+key][2048 + h*64 + d]  (bf16->bf16)
// grid: (64 key-tiles, 2 dim-tiles, 64 bh)
// ---------------------------------------------------------------------------
__global__ __launch_bounds__(256) void vtprep_kernel(const short* __restrict__ qkv,
                                                     short* __restrict__ vt) {
    __shared__ short tile[32][33];
    int tx = threadIdx.x & 31, ty = threadIdx.x >> 5;
    int bh = blockIdx.z, b = bh >> 4, h = bh & 15;
    int k0 = blockIdx.x * 32, d0 = blockIdx.y * 32;
#pragma unroll
    for (int i = 0; i < 4; i++)
        tile[ty + i * 8][tx] =
            qkv[(size_t)(b * 2048 + k0 + ty + i * 8) * 3072 + 2048 + h * 64 + d0 + tx];
    __syncthreads();
#pragma unroll
    for (int i = 0; i < 4; i++)
        vt[(size_t)bh * 131072 + (size_t)(d0 + ty + i * 8) * 2048 + k0 + tx] =
            tile[tx][ty + i * 8];
}

// ---------------------------------------------------------------------------
// GEMM (BK=32): C[M,N] = A[M,K](bf16) * Bt[N,K]^T(bf16) (+bias) (relu) (+res)
// m97 structure: global_load_lds width=16 into unpadded LDS [128][32],
// XOR chunk swizzle (c ^= (row>>1)&3) -> 0 bank conflicts (measured r3).
// block 256 = 4 waves (2x2), tile 128x128, mfma 16x16x32 bf16.
// Used for the high-block-count GEMMs (QKV, FF1).
// ---------------------------------------------------------------------------
template <int RELU, int OUTF32>
__global__ __launch_bounds__(256) void gemm_bt(const short* __restrict__ A,
                                               const short* __restrict__ Bt,
                                               const float* __restrict__ bias,
                                               const float* __restrict__ res,
                                               void* __restrict__ Cout,
                                               int M, int N, int K) {
    __shared__ short lA[128 * 32];
    __shared__ short lB[128 * 32];
    int t = threadIdx.x;
    int bn = blockIdx.x, bm = blockIdx.y;
    int w = t >> 6, lane = t & 63, quad = lane >> 4, l15 = lane & 15;
    int wm = (w >> 1) * 64, wn = (w & 1) * 64;
    floatx4 acc[4][4] = {};
    const int nkt = K >> 5;
    int S0 = w * 64 + lane, S1 = 256 + S0;
    int r0 = S0 >> 2, c0 = (S0 & 3) ^ ((r0 >> 1) & 3);
    int r1 = S1 >> 2, c1 = (S1 & 3) ^ ((r1 >> 1) & 3);
    const short* Ag0 = A + (size_t)(bm * 128 + r0) * K + c0 * 8;
    const short* Ag1 = A + (size_t)(bm * 128 + r1) * K + c1 * 8;
    const short* Bg0 = Bt + (size_t)(bn * 128 + r0) * K + c0 * 8;
    const short* Bg1 = Bt + (size_t)(bn * 128 + r1) * K + c1 * 8;
    short* lA0 = &lA[S0 * 8]; short* lA1 = &lA[S1 * 8];
    short* lB0 = &lB[S0 * 8]; short* lB1 = &lB[S1 * 8];
    for (int kt = 0; kt < nkt; kt++) {
        g2l16(Ag0 + kt * 32, lA0);
        g2l16(Ag1 + kt * 32, lA1);
        g2l16(Bg0 + kt * 32, lB0);
        g2l16(Bg1 + kt * 32, lB1);
        __syncthreads();   // drains vmcnt(0): staged data visible
        short8 af[4], bf[4];
#pragma unroll
        for (int mt = 0; mt < 4; mt++) {
            int row = wm + mt * 16 + l15;
            int c = quad ^ ((row >> 1) & 3);
            af[mt] = *(short8*)&lA[row * 32 + c * 8];
        }
#pragma unroll
        for (int nt = 0; nt < 4; nt++) {
            int row = wn + nt * 16 + l15;
            int c = quad ^ ((row >> 1) & 3);
            bf[nt] = *(short8*)&lB[row * 32 + c * 8];
        }
#pragma unroll
        for (int mt = 0; mt < 4; mt++)
#pragma unroll
            for (int nt = 0; nt < 4; nt++)
                acc[mt][nt] = __builtin_amdgcn_mfma_f32_16x16x32_bf16(
                    af[mt], bf[nt], acc[mt][nt], 0, 0, 0);
        __syncthreads();
    }
#pragma unroll
    for (int mt = 0; mt < 4; mt++) {
#pragma unroll
        for (int nt = 0; nt < 4; nt++) {
            int col = bn * 128 + wn + nt * 16 + l15;
            float bv = bias ? bias[col] : 0.0f;
#pragma unroll
            for (int r = 0; r < 4; r++) {
                int row = bm * 128 + wm + mt * 16 + quad * 4 + r;
                float v = acc[mt][nt][r] + bv;
                if (RELU) v = fmaxf(v, 0.0f);
                if (res) v += res[(size_t)row * N + col];
                if (OUTF32)
                    ((float*)Cout)[(size_t)row * N + col] = v;
                else
                    ((short*)Cout)[(size_t)row * N + col] = f2b(v);
            }
        }
    }
}

// ---------------------------------------------------------------------------
// GEMM (BK=64): for grid-limited N=1024 cases (Wout, FF2: 512 blocks = only
// 2 blocks/CU, can't add blocks). Doubles MFMA-per-barrier (32) and
// bytes-in-flight (8 g2l16/lane, 64KB/CU at 2 blocks) to amortize the
// vmcnt(0)+barrier drain. LDS 32KB/block: no occupancy loss at 2 blocks/CU.
// Row stride 64 elems (128B); swizzle chunk c ^= row&7 -> 2-way (free).
// ---------------------------------------------------------------------------
template <int RELU, int OUTF32>
__global__ __launch_bounds__(256) void gemm_bt_k64(const short* __restrict__ A,
                                                   const short* __restrict__ Bt,
                                                   const float* __restrict__ bias,
                                                   const float* __restrict__ res,
                                                   void* __restrict__ Cout,
                                                   int M, int N, int K) {
    __shared__ short lA[128 * 64];
    __shared__ short lB[128 * 64];
    int t = threadIdx.x;
    int bn = blockIdx.x, bm = blockIdx.y;
    int w = t >> 6, lane = t & 63, quad = lane >> 4, l15 = lane & 15;
    int wm = (w >> 1) * 64, wn = (w & 1) * 64;
    floatx4 acc[4][4] = {};
    const int nkt = K >> 6;
    // 1024 16B chunks per buffer; each lane stages 4 per buffer
    const short* Ag[4]; const short* Bg[4];
    short* lAp[4]; short* lBp[4];
#pragma unroll
    for (int i = 0; i < 4; i++) {
        int S = i * 256 + t;
        int r = S >> 3, c = (S & 7) ^ (r & 7);
        Ag[i] = A + (size_t)(bm * 128 + r) * K + c * 8;
        Bg[i] = Bt + (size_t)(bn * 128 + r) * K + c * 8;
        lAp[i] = &lA[S * 8];
        lBp[i] = &lB[S * 8];
    }
    for (int kt = 0; kt < nkt; kt++) {
#pragma unroll
        for (int i = 0; i < 4; i++) {
            g2l16(Ag[i] + kt * 64, lAp[i]);
            g2l16(Bg[i] + kt * 64, lBp[i]);
        }
        __syncthreads();   // drains vmcnt(0)
        short8 af[2][4], bf[2][4];
#pragma unroll
        for (int kc = 0; kc < 2; kc++) {
#pragma unroll
            for (int mt = 0; mt < 4; mt++) {
                int row = wm + mt * 16 + l15;
                int c = (kc * 4 + quad) ^ (row & 7);
                af[kc][mt] = *(short8*)&lA[row * 64 + c * 8];
            }
#pragma unroll
            for (int nt = 0; nt < 4; nt++) {
                int row = wn + nt * 16 + l15;
                int c = (kc * 4 + quad) ^ (row & 7);
                bf[kc][nt] = *(short8*)&lB[row * 64 + c * 8];
            }
        }
#pragma unroll
        for (int kc = 0; kc < 2; kc++)
#pragma unroll
            for (int mt = 0; mt < 4; mt++)
#pragma unroll
                for (int nt = 0; nt < 4; nt++)
                    acc[mt][nt] = __builtin_amdgcn_mfma_f32_16x16x32_bf16(
                        af[kc][mt], bf[kc][nt], acc[mt][nt], 0, 0, 0);
        __syncthreads();
    }
#pragma unroll
    for (int mt = 0; mt < 4; mt++) {
#pragma unroll
        for (int nt = 0; nt < 4; nt++) {
            int col = bn * 128 + wn + nt * 16 + l15;
            float bv = bias ? bias[col] : 0.0f;
#pragma unroll
            for (int r = 0; r < 4; r++) {
                int row = bm * 128 + wm + mt * 16 + quad * 4 + r;
                float v = acc[mt][nt][r] + bv;
                if (RELU) v = fmaxf(v, 0.0f);
                if (res) v += res[(size_t)row * N + col];
                if (OUTF32)
                    ((float*)Cout)[(size_t)row * N + col] = v;
                else
                    ((short*)Cout)[(size_t)row * N + col] = f2b(v);
            }
        }
    }
}

// ---------------------------------------------------------------------------
// Flash attention: grid (16 qtiles, 16 heads, 4 batch), block 256 = 4 waves
// each wave: 32 queries x 64 dims; K-tiles of 64 keys.
// No running max (|S/32| << 88). Q prescaled by 2^-5 (exact in bf16), so the
// softmax inner loop is just __expf + sum-add + v_perm truncation pack.
// lK rows key-permuted (row j holds key (j&15)*4+(j>>4)) -> P writes are one
// b64 per 4 contiguous k'. K/V staged via global_load_lds, XOR swizzle.
// ---------------------------------------------------------------------------
__global__ __launch_bounds__(256) void attn_kernel(const short* __restrict__ qkv,
                                                   const short* __restrict__ vt,
                                                   short* __restrict__ out) {
    __shared__ short lK[64 * 64];
    __shared__ short lV[64 * 64];
    __shared__ short lP[4 * 32 * 72];
    int t = threadIdx.x;
    int w = t >> 6, lane = t & 63, quad = lane >> 4, l15 = lane & 15;
    int qt = blockIdx.x, h = blockIdx.y, b = blockIdx.z;
    int qrow0 = b * 2048 + qt * 128 + w * 32;
    short* lPw = &lP[w * 32 * 72];

    // Q fragments, prescaled by SCALE = 2^-5 (exact in bf16)
    short8 qf[2][2];
#pragma unroll
    for (int mt = 0; mt < 2; mt++)
#pragma unroll
        for (int kc = 0; kc < 2; kc++) {
            short8 q = *(const short8*)(qkv + (size_t)(qrow0 + mt * 16 + l15) * 3072 +
                                        h * 64 + kc * 32 + quad * 8);
#pragma unroll
            for (int i = 0; i < 8; i++) q[i] = f2b(b2f(q[i]) * 0.03125f);
            qf[mt][kc] = q;
        }

    float l_s[2][4] = {};
    floatx4 o[2][4] = {};

    int S0 = w * 64 + lane, S1 = 256 + S0;
    int r0 = S0 >> 3, c0 = (S0 & 7) ^ (r0 & 7);
    int r1 = S1 >> 3, c1 = (S1 & 7) ^ (r1 & 7);
    int kr0 = (r0 & 15) * 4 + (r0 >> 4);
    int kr1 = (r1 & 15) * 4 + (r1 >> 4);
    const short* Kg0 = qkv + (size_t)(b * 2048 + kr0) * 3072 + 1024 + h * 64 + c0 * 8;
    const short* Kg1 = qkv + (size_t)(b * 2048 + kr1) * 3072 + 1024 + h * 64 + c1 * 8;
    const short* Vg0 = vt + (size_t)(b * 16 + h) * 131072 + (size_t)r0 * 2048 + c0 * 8;
    const short* Vg1 = vt + (size_t)(b * 16 + h) * 131072 + (size_t)r1 * 2048 + c1 * 8;
    short* lK0 = &lK[S0 * 8]; short* lK1 = &lK[S1 * 8];
    short* lV0 = &lV[S0 * 8]; short* lV1 = &lV[S1 * 8];

    for (int kt = 0; kt < 32; kt++) {
        __syncthreads();
        int key0 = kt * 64;
        g2l16(Kg0 + (size_t)key0 * 3072, lK0);
        g2l16(Kg1 + (size_t)key0 * 3072, lK1);
        g2l16(Vg0 + key0, lV0);
        g2l16(Vg1 + key0, lV1);
        __syncthreads();

        // S = (Q*2^-5) K^T   (col (nt,l15) is key k' = l15*4+nt)
        floatx4 s[2][4] = {};
#pragma unroll
        for (int kc = 0; kc < 2; kc++) {
            short8 kf[4];
#pragma unroll
            for (int nt = 0; nt < 4; nt++) {
                int row = nt * 16 + l15;
                int c = (kc * 4 + quad) ^ (row & 7);
                kf[nt] = *(short8*)&lK[row * 64 + c * 8];
            }
#pragma unroll
            for (int mt = 0; mt < 2; mt++)
#pragma unroll
                for (int nt = 0; nt < 4; nt++)
                    s[mt][nt] = __builtin_amdgcn_mfma_f32_16x16x32_bf16(
                        qf[mt][kc], kf[nt], s[mt][nt], 0, 0, 0);
        }

        // p = exp(S); lane-local partial row-sum; truncation-pack to bf16
#pragma unroll
        for (int mt = 0; mt < 2; mt++) {
#pragma unroll
            for (int r = 0; r < 4; r++) {
                float p0 = __expf(s[mt][0][r]);
                float p1 = __expf(s[mt][1][r]);
                float p2 = __expf(s[mt][2][r]);
                float p3 = __expf(s[mt][3][r]);
                l_s[mt][r] += (p0 + p1) + (p2 + p3);
                uint2 pk;
                pk.x = __builtin_amdgcn_perm(__float_as_uint(p1),
                                             __float_as_uint(p0), 0x07060302u);
                pk.y = __builtin_amdgcn_perm(__float_as_uint(p3),
                                             __float_as_uint(p2), 0x07060302u);
                *(uint2*)&lPw[(mt * 16 + quad * 4 + r) * 72 + l15 * 4] = pk;
            }
        }
        // lP is wave-private: no barrier needed

        // O += P V
#pragma unroll
        for (int kc = 0; kc < 2; kc++) {
            short8 pf[2], vf[4];
#pragma unroll
            for (int mt = 0; mt < 2; mt++)
                pf[mt] = *(short8*)&lPw[(mt * 16 + l15) * 72 + kc * 32 + quad * 8];
#pragma unroll
            for (int nt = 0; nt < 4; nt++) {
                int row = nt * 16 + l15;
                int c = (kc * 4 + quad) ^ (row & 7);
                vf[nt] = *(short8*)&lV[row * 64 + c * 8];
            }
#pragma unroll
            for (int mt = 0; mt < 2; mt++)
#pragma unroll
                for (int nt = 0; nt < 4; nt++)
                    o[mt][nt] = __builtin_amdgcn_mfma_f32_16x16x32_bf16(
                        pf[mt], vf[nt], o[mt][nt], 0, 0, 0);
        }
    }

#pragma unroll
    for (int mt = 0; mt < 2; mt++)
#pragma unroll
        for (int r = 0; r < 4; r++) {
            float v = l_s[mt][r];
            v += __shfl_xor(v, 1); v += __shfl_xor(v, 2);
            v += __shfl_xor(v, 4); v += __shfl_xor(v, 8);
            l_s[mt][r] = v;
        }

#pragma unroll
    for (int mt = 0; mt < 2; mt++)
#pragma unroll
        for (int nt = 0; nt < 4; nt++)
#pragma unroll
            for (int r = 0; r < 4; r++) {
                int row = qrow0 + mt * 16 + quad * 4 + r;
                int col = h * 64 + nt * 16 + l15;
                out[(size_t)row * 1024 + col] = f2b(o[mt][nt][r] / l_s[mt][r]);
            }
}

// ---------------------------------------------------------------------------
extern "C" void kernel_launch(void* const* d_in, const int* in_sizes, int n_in,
                              void* d_out, int out_size, void* d_ws, size_t ws_size,
                              hipStream_t stream) {
    const float* x      = (const float*)d_in[0];
    const float* w_qkv  = (const float*)d_in[1];
    const float* w_out  = (const float*)d_in[2];
    const float* b_out  = (const float*)d_in[3];
    const float* w1     = (const float*)d_in[4];
    const float* b1     = (const float*)d_in[5];
    const float* w2     = (const float*)d_in[6];
    const float* b2     = (const float*)d_in[7];
    const float* gamma1 = (const float*)d_in[8];
    const float* beta1  = (const float*)d_in[9];
    const float* gamma2 = (const float*)d_in[10];
    const float* beta2  = (const float*)d_in[11];
    float* out = (float*)d_out;

    // Workspace layout (byte offsets, 136MB high-water):
    //   0: wqkvT 6MB | 6: woutT 2MB | 8: w1T 8MB | 16: w2T 8MB
    //  24: h1 16MB (LN1 out -> attn out -> LN2 out)
    //  40: qkv 48MB + 88: vt 16MB  (both dead after attn; ff1 64MB spans both)
    // 104: x2 fp32 32MB (live to end)
    char* ws = (char*)d_ws;
    const size_t MB = 1024u * 1024u;
    short* wqkvT = (short*)(ws + 0 * MB);
    short* woutT = (short*)(ws + 6 * MB);
    short* w1T   = (short*)(ws + 8 * MB);
    short* w2T   = (short*)(ws + 16 * MB);
    short* h1    = (short*)(ws + 24 * MB);
    short* qkv   = (short*)(ws + 40 * MB);
    short* vt    = (short*)(ws + 88 * MB);
    short* ff1   = (short*)(ws + 40 * MB);
    float* x2    = (float*)(ws + 104 * MB);
    short* attn  = h1;   // h1 dead after QKV gemm
    short* h2    = h1;   // attn out dead after Wout gemm

    dim3 blk(256);
    transpose_w<<<dim3(96, 32), blk, 0, stream>>>(w_qkv, wqkvT, 1024, 3072);
    transpose_w<<<dim3(32, 32), blk, 0, stream>>>(w_out, woutT, 1024, 1024);
    transpose_w<<<dim3(128, 32), blk, 0, stream>>>(w1, w1T, 1024, 4096);
    transpose_w<<<dim3(32, 128), blk, 0, stream>>>(w2, w2T, 4096, 1024);

    ln_kernel<<<8192, blk, 0, stream>>>(x, gamma1, beta1, h1);
    gemm_bt<0, 0><<<dim3(24, 64), blk, 0, stream>>>(h1, wqkvT, nullptr, nullptr, qkv,
                                                    8192, 3072, 1024);
    vtprep_kernel<<<dim3(64, 2, 64), blk, 0, stream>>>(qkv, vt);
    attn_kernel<<<dim3(16, 16, 4), blk, 0, stream>>>(qkv, vt, attn);
    gemm_bt_k64<0, 1><<<dim3(8, 64), blk, 0, stream>>>(attn, woutT, b_out, x, x2,
                                                       8192, 1024, 1024);
    ln_kernel<<<8192, blk, 0, stream>>>(x2, gamma2, beta2, h2);
    gemm_bt<1, 0><<<dim3(32, 64), blk, 0, stream>>>(h2, w1T, b1, nullptr, ff1,
                                                    8192, 4096, 1024);
    gemm_bt_k64<0, 1><<<dim3(8, 64), blk, 0, stream>>>(ff1, w2T, b2, x2, out,
                                                       8192, 1024, 4096);
}

// Round 6
// 563.335 us; speedup vs baseline: 1.1265x; 1.0161x over previous
//
#include <hip/hip_runtime.h>
#include <hip/hip_bf16.h>
#include <stdint.h>

// Harness contract: reference is pure fp32 => all d_in are float*, d_out is
// float*. We convert to bf16 internally for MFMA, accumulate fp32.

typedef __attribute__((ext_vector_type(8))) short short8;   // 8 bf16 = 4 VGPRs (MFMA A/B frag)
typedef __attribute__((ext_vector_type(4))) short short4v;  // 4 bf16 = 8B
typedef __attribute__((ext_vector_type(4))) float floatx4;  // MFMA C/D frag

#define DEV static __device__ __forceinline__

DEV float b2f(short s) {
    unsigned u = ((unsigned)(unsigned short)s) << 16;
    return __uint_as_float(u);
}
DEV short f2b(float f) {  // round-to-nearest-even bf16
    unsigned u = __float_as_uint(f);
    u += 0x7fffu + ((u >> 16) & 1u);
    return (short)(u >> 16);
}

// async global->LDS, 16B per lane; HW writes lane i at wavebase + i*16
// (pass per-lane LDS ptr = base + lane*16 so source layout matches HW).
typedef const __attribute__((address_space(1))) unsigned gu32;
typedef __attribute__((address_space(3))) unsigned lu32;
DEV void g2l16(const void* g, void* l) {
    __builtin_amdgcn_global_load_lds((gu32*)(uintptr_t)g,
                                     (lu32*)(unsigned)(uintptr_t)l, 16, 0, 0);
}

// ---------------------------------------------------------------------------
// LayerNorm: y = gamma*(x-mean)/(std+eps)+beta, std = sqrt(sum((x-m)^2)/(n-1))
// fp32 in, bf16 out. one row (1024) per block of 256 threads
// ---------------------------------------------------------------------------
__global__ __launch_bounds__(256) void ln_kernel(const float* __restrict__ x,
                                                 const float* __restrict__ gamma,
                                                 const float* __restrict__ beta,
                                                 short* __restrict__ y) {
    int row = blockIdx.x;
    int t = threadIdx.x;
    float4 v = *(const float4*)(x + (size_t)row * 1024 + t * 4);
    float f[4] = {v.x, v.y, v.z, v.w};
    float s = 0.f, ss = 0.f;
#pragma unroll
    for (int i = 0; i < 4; i++) { s += f[i]; ss += f[i] * f[i]; }
#pragma unroll
    for (int off = 32; off; off >>= 1) { s += __shfl_xor(s, off); ss += __shfl_xor(ss, off); }
    __shared__ float rs[4], rss[4];
    int wid = t >> 6, lane = t & 63;
    if (lane == 0) { rs[wid] = s; rss[wid] = ss; }
    __syncthreads();
    s = rs[0] + rs[1] + rs[2] + rs[3];
    ss = rss[0] + rss[1] + rss[2] + rss[3];
    float mean = s * (1.0f / 1024.0f);
    float var = (ss - 1024.0f * mean * mean) * (1.0f / 1023.0f);
    var = fmaxf(var, 0.0f);
    float inv = 1.0f / (sqrtf(var) + 1e-5f);
    float4 g = *(const float4*)(gamma + t * 4);
    float4 bb = *(const float4*)(beta + t * 4);
    short4v o;
    o[0] = f2b(g.x * (f[0] - mean) * inv + bb.x);
    o[1] = f2b(g.y * (f[1] - mean) * inv + bb.y);
    o[2] = f2b(g.z * (f[2] - mean) * inv + bb.z);
    o[3] = f2b(g.w * (f[3] - mean) * inv + bb.w);
    *(short4v*)(y + (size_t)row * 1024 + t * 4) = o;
}

// ---------------------------------------------------------------------------
// Weight transpose + fp32->bf16: out[c*R + r] = bf16(in[r*C + c])
// ---------------------------------------------------------------------------
__global__ __launch_bounds__(256) void transpose_w(const float* __restrict__ in,
                                                   short* __restrict__ out,
                                                   int R, int C) {
    __shared__ short tile[32][33];
    int tx = threadIdx.x & 31, ty = threadIdx.x >> 5;
    int c0 = blockIdx.x * 32, r0 = blockIdx.y * 32;
#pragma unroll
    for (int i = 0; i < 4; i++)
        tile[ty + i * 8][tx] = f2b(in[(size_t)(r0 + ty + i * 8) * C + c0 + tx]);
    __syncthreads();
#pragma unroll
    for (int i = 0; i < 4; i++)
        out[(size_t)(c0 + ty + i * 8) * R + r0 + tx] = tile[tx][ty + i * 8];
}

// ---------------------------------------------------------------------------
// V^T prep: vt[bh][d][key] = qkv[b*2048+key][2048 + h*64 + d]  (bf16->bf16)
// grid: (64 key-tiles, 2 dim-tiles, 64 bh)
// ---------------------------------------------------------------------------
__global__ __launch_bounds__(256) void vtprep_kernel(const short* __restrict__ qkv,
                                                     short* __restrict__ vt) {
    __shared__ short tile[32][33];
    int tx = threadIdx.x & 31, ty = threadIdx.x >> 5;
    int bh = blockIdx.z, b = bh >> 4, h = bh & 15;
    int k0 = blockIdx.x * 32, d0 = blockIdx.y * 32;
#pragma unroll
    for (int i = 0; i < 4; i++)
        tile[ty + i * 8][tx] =
            qkv[(size_t)(b * 2048 + k0 + ty + i * 8) * 3072 + 2048 + h * 64 + d0 + tx];
    __syncthreads();
#pragma unroll
    for (int i = 0; i < 4; i++)
        vt[(size_t)bh * 131072 + (size_t)(d0 + ty + i * 8) * 2048 + k0 + tx] =
            tile[tx][ty + i * 8];
}

// ---------------------------------------------------------------------------
// GEMM (BK=64): C[M,N] = A[M,K](bf16) * Bt[N,K]^T(bf16) (+bias) (relu) (+res)
// Tile 128x128, 4 waves (2x2), 32 MFMA + 8 g2l16/lane per barrier pair.
// BK=64 beat BK=32 by ~30% on the grid-limited GEMMs (r4->r5) by doubling
// bytes-in-flight and MFMA-per-barrier-drain at unchanged occupancy; now
// standardized for all four GEMMs. LDS 32KB/block -> 5 blocks/CU ceiling.
// Row stride 64 elems (128B); swizzle chunk c ^= row&7 -> measured 0 conflicts.
// ---------------------------------------------------------------------------
template <int RELU, int OUTF32>
__global__ __launch_bounds__(256) void gemm_bt_k64(const short* __restrict__ A,
                                                   const short* __restrict__ Bt,
                                                   const float* __restrict__ bias,
                                                   const float* __restrict__ res,
                                                   void* __restrict__ Cout,
                                                   int M, int N, int K) {
    __shared__ short lA[128 * 64];
    __shared__ short lB[128 * 64];
    int t = threadIdx.x;
    int bn = blockIdx.x, bm = blockIdx.y;
    int w = t >> 6, lane = t & 63, quad = lane >> 4, l15 = lane & 15;
    int wm = (w >> 1) * 64, wn = (w & 1) * 64;
    floatx4 acc[4][4] = {};
    const int nkt = K >> 6;
    // 1024 16B chunks per buffer; each lane stages 4 per buffer
    const short* Ag[4]; const short* Bg[4];
    short* lAp[4]; short* lBp[4];
#pragma unroll
    for (int i = 0; i < 4; i++) {
        int S = i * 256 + t;
        int r = S >> 3, c = (S & 7) ^ (r & 7);
        Ag[i] = A + (size_t)(bm * 128 + r) * K + c * 8;
        Bg[i] = Bt + (size_t)(bn * 128 + r) * K + c * 8;
        lAp[i] = &lA[S * 8];
        lBp[i] = &lB[S * 8];
    }
    for (int kt = 0; kt < nkt; kt++) {
#pragma unroll
        for (int i = 0; i < 4; i++) {
            g2l16(Ag[i] + kt * 64, lAp[i]);
            g2l16(Bg[i] + kt * 64, lBp[i]);
        }
        __syncthreads();   // drains vmcnt(0)
        short8 af[2][4], bf[2][4];
#pragma unroll
        for (int kc = 0; kc < 2; kc++) {
#pragma unroll
            for (int mt = 0; mt < 4; mt++) {
                int row = wm + mt * 16 + l15;
                int c = (kc * 4 + quad) ^ (row & 7);
                af[kc][mt] = *(short8*)&lA[row * 64 + c * 8];
            }
#pragma unroll
            for (int nt = 0; nt < 4; nt++) {
                int row = wn + nt * 16 + l15;
                int c = (kc * 4 + quad) ^ (row & 7);
                bf[kc][nt] = *(short8*)&lB[row * 64 + c * 8];
            }
        }
#pragma unroll
        for (int kc = 0; kc < 2; kc++)
#pragma unroll
            for (int mt = 0; mt < 4; mt++)
#pragma unroll
                for (int nt = 0; nt < 4; nt++)
                    acc[mt][nt] = __builtin_amdgcn_mfma_f32_16x16x32_bf16(
                        af[kc][mt], bf[kc][nt], acc[mt][nt], 0, 0, 0);
        __syncthreads();
    }
#pragma unroll
    for (int mt = 0; mt < 4; mt++) {
#pragma unroll
        for (int nt = 0; nt < 4; nt++) {
            int col = bn * 128 + wn + nt * 16 + l15;
            float bv = bias ? bias[col] : 0.0f;
#pragma unroll
            for (int r = 0; r < 4; r++) {
                int row = bm * 128 + wm + mt * 16 + quad * 4 + r;
                float v = acc[mt][nt][r] + bv;
                if (RELU) v = fmaxf(v, 0.0f);
                if (res) v += res[(size_t)row * N + col];
                if (OUTF32)
                    ((float*)Cout)[(size_t)row * N + col] = v;
                else
                    ((short*)Cout)[(size_t)row * N + col] = f2b(v);
            }
        }
    }
}

// ---------------------------------------------------------------------------
// Flash attention: grid (16 qtiles, 16 heads, 4 batch), block 256 = 4 waves
// each wave: 32 queries x 64 dims; K-tiles of 64 keys.
// No running max (|S/32| << 88). Q prescaled by 2^-5 (exact in bf16), so the
// softmax inner loop is just __expf + sum-add + v_perm truncation pack.
// lK rows key-permuted (row j holds key (j&15)*4+(j>>4)) -> P writes are one
// b64 per 4 contiguous k'. K/V staged via global_load_lds, XOR swizzle.
// ---------------------------------------------------------------------------
__global__ __launch_bounds__(256) void attn_kernel(const short* __restrict__ qkv,
                                                   const short* __restrict__ vt,
                                                   short* __restrict__ out) {
    __shared__ short lK[64 * 64];
    __shared__ short lV[64 * 64];
    __shared__ short lP[4 * 32 * 72];
    int t = threadIdx.x;
    int w = t >> 6, lane = t & 63, quad = lane >> 4, l15 = lane & 15;
    int qt = blockIdx.x, h = blockIdx.y, b = blockIdx.z;
    int qrow0 = b * 2048 + qt * 128 + w * 32;
    short* lPw = &lP[w * 32 * 72];

    // Q fragments, prescaled by SCALE = 2^-5 (exact in bf16)
    short8 qf[2][2];
#pragma unroll
    for (int mt = 0; mt < 2; mt++)
#pragma unroll
        for (int kc = 0; kc < 2; kc++) {
            short8 q = *(const short8*)(qkv + (size_t)(qrow0 + mt * 16 + l15) * 3072 +
                                        h * 64 + kc * 32 + quad * 8);
#pragma unroll
            for (int i = 0; i < 8; i++) q[i] = f2b(b2f(q[i]) * 0.03125f);
            qf[mt][kc] = q;
        }

    float l_s[2][4] = {};
    floatx4 o[2][4] = {};

    int S0 = w * 64 + lane, S1 = 256 + S0;
    int r0 = S0 >> 3, c0 = (S0 & 7) ^ (r0 & 7);
    int r1 = S1 >> 3, c1 = (S1 & 7) ^ (r1 & 7);
    int kr0 = (r0 & 15) * 4 + (r0 >> 4);
    int kr1 = (r1 & 15) * 4 + (r1 >> 4);
    const short* Kg0 = qkv + (size_t)(b * 2048 + kr0) * 3072 + 1024 + h * 64 + c0 * 8;
    const short* Kg1 = qkv + (size_t)(b * 2048 + kr1) * 3072 + 1024 + h * 64 + c1 * 8;
    const short* Vg0 = vt + (size_t)(b * 16 + h) * 131072 + (size_t)r0 * 2048 + c0 * 8;
    const short* Vg1 = vt + (size_t)(b * 16 + h) * 131072 + (size_t)r1 * 2048 + c1 * 8;
    short* lK0 = &lK[S0 * 8]; short* lK1 = &lK[S1 * 8];
    short* lV0 = &lV[S0 * 8]; short* lV1 = &lV[S1 * 8];

    for (int kt = 0; kt < 32; kt++) {
        __syncthreads();
        int key0 = kt * 64;
        g2l16(Kg0 + (size_t)key0 * 3072, lK0);
        g2l16(Kg1 + (size_t)key0 * 3072, lK1);
        g2l16(Vg0 + key0, lV0);
        g2l16(Vg1 + key0, lV1);
        __syncthreads();

        // S = (Q*2^-5) K^T   (col (nt,l15) is key k' = l15*4+nt)
        floatx4 s[2][4] = {};
#pragma unroll
        for (int kc = 0; kc < 2; kc++) {
            short8 kf[4];
#pragma unroll
            for (int nt = 0; nt < 4; nt++) {
                int row = nt * 16 + l15;
                int c = (kc * 4 + quad) ^ (row & 7);
                kf[nt] = *(short8*)&lK[row * 64 + c * 8];
            }
#pragma unroll
            for (int mt = 0; mt < 2; mt++)
#pragma unroll
                for (int nt = 0; nt < 4; nt++)
                    s[mt][nt] = __builtin_amdgcn_mfma_f32_16x16x32_bf16(
                        qf[mt][kc], kf[nt], s[mt][nt], 0, 0, 0);
        }

        // p = exp(S); lane-local partial row-sum; truncation-pack to bf16
#pragma unroll
        for (int mt = 0; mt < 2; mt++) {
#pragma unroll
            for (int r = 0; r < 4; r++) {
                float p0 = __expf(s[mt][0][r]);
                float p1 = __expf(s[mt][1][r]);
                float p2 = __expf(s[mt][2][r]);
                float p3 = __expf(s[mt][3][r]);
                l_s[mt][r] += (p0 + p1) + (p2 + p3);
                uint2 pk;
                pk.x = __builtin_amdgcn_perm(__float_as_uint(p1),
                                             __float_as_uint(p0), 0x07060302u);
                pk.y = __builtin_amdgcn_perm(__float_as_uint(p3),
                                             __float_as_uint(p2), 0x07060302u);
                *(uint2*)&lPw[(mt * 16 + quad * 4 + r) * 72 + l15 * 4] = pk;
            }
        }
        // lP is wave-private: no barrier needed

        // O += P V
#pragma unroll
        for (int kc = 0; kc < 2; kc++) {
            short8 pf[2], vf[4];
#pragma unroll
            for (int mt = 0; mt < 2; mt++)
                pf[mt] = *(short8*)&lPw[(mt * 16 + l15) * 72 + kc * 32 + quad * 8];
#pragma unroll
            for (int nt = 0; nt < 4; nt++) {
                int row = nt * 16 + l15;
                int c = (kc * 4 + quad) ^ (row & 7);
                vf[nt] = *(short8*)&lV[row * 64 + c * 8];
            }
#pragma unroll
            for (int mt = 0; mt < 2; mt++)
#pragma unroll
                for (int nt = 0; nt < 4; nt++)
                    o[mt][nt] = __builtin_amdgcn_mfma_f32_16x16x32_bf16(
                        pf[mt], vf[nt], o[mt][nt], 0, 0, 0);
        }
    }

#pragma unroll
    for (int mt = 0; mt < 2; mt++)
#pragma unroll
        for (int r = 0; r < 4; r++) {
            float v = l_s[mt][r];
            v += __shfl_xor(v, 1); v += __shfl_xor(v, 2);
            v += __shfl_xor(v, 4); v += __shfl_xor(v, 8);
            l_s[mt][r] = v;
        }

#pragma unroll
    for (int mt = 0; mt < 2; mt++)
#pragma unroll
        for (int nt = 0; nt < 4; nt++)
#pragma unroll
            for (int r = 0; r < 4; r++) {
                int row = qrow0 + mt * 16 + quad * 4 + r;
                int col = h * 64 + nt * 16 + l15;
                out[(size_t)row * 1024 + col] = f2b(o[mt][nt][r] / l_s[mt][r]);
            }
}

// ---------------------------------------------------------------------------
extern "C" void kernel_launch(void* const* d_in, const int* in_sizes, int n_in,
                              void* d_out, int out_size, void* d_ws, size_t ws_size,
                              hipStream_t stream) {
    const float* x      = (const float*)d_in[0];
    const float* w_qkv  = (const float*)d_in[1];
    const float* w_out  = (const float*)d_in[2];
    const float* b_out  = (const float*)d_in[3];
    const float* w1     = (const float*)d_in[4];
    const float* b1     = (const float*)d_in[5];
    const float* w2     = (const float*)d_in[6];
    const float* b2     = (const float*)d_in[7];
    const float* gamma1 = (const float*)d_in[8];
    const float* beta1  = (const float*)d_in[9];
    const float* gamma2 = (const float*)d_in[10];
    const float* beta2  = (const float*)d_in[11];
    float* out = (float*)d_out;

    // Workspace layout (byte offsets, 136MB high-water):
    //   0: wqkvT 6MB | 6: woutT 2MB | 8: w1T 8MB | 16: w2T 8MB
    //  24: h1 16MB (LN1 out -> attn out -> LN2 out)
    //  40: qkv 48MB + 88: vt 16MB  (both dead after attn; ff1 64MB spans both)
    // 104: x2 fp32 32MB (live to end)
    char* ws = (char*)d_ws;
    const size_t MB = 1024u * 1024u;
    short* wqkvT = (short*)(ws + 0 * MB);
    short* woutT = (short*)(ws + 6 * MB);
    short* w1T   = (short*)(ws + 8 * MB);
    short* w2T   = (short*)(ws + 16 * MB);
    short* h1    = (short*)(ws + 24 * MB);
    short* qkv   = (short*)(ws + 40 * MB);
    short* vt    = (short*)(ws + 88 * MB);
    short* ff1   = (short*)(ws + 40 * MB);
    float* x2    = (float*)(ws + 104 * MB);
    short* attn  = h1;   // h1 dead after QKV gemm
    short* h2    = h1;   // attn out dead after Wout gemm

    dim3 blk(256);
    transpose_w<<<dim3(96, 32), blk, 0, stream>>>(w_qkv, wqkvT, 1024, 3072);
    transpose_w<<<dim3(32, 32), blk, 0, stream>>>(w_out, woutT, 1024, 1024);
    transpose_w<<<dim3(128, 32), blk, 0, stream>>>(w1, w1T, 1024, 4096);
    transpose_w<<<dim3(32, 128), blk, 0, stream>>>(w2, w2T, 4096, 1024);

    ln_kernel<<<8192, blk, 0, stream>>>(x, gamma1, beta1, h1);
    gemm_bt_k64<0, 0><<<dim3(24, 64), blk, 0, stream>>>(h1, wqkvT, nullptr, nullptr,
                                                        qkv, 8192, 3072, 1024);
    vtprep_kernel<<<dim3(64, 2, 64), blk, 0, stream>>>(qkv, vt);
    attn_kernel<<<dim3(16, 16, 4), blk, 0, stream>>>(qkv, vt, attn);
    gemm_bt_k64<0, 1><<<dim3(8, 64), blk, 0, stream>>>(attn, woutT, b_out, x, x2,
                                                       8192, 1024, 1024);
    ln_kernel<<<8192, blk, 0, stream>>>(x2, gamma2, beta2, h2);
    gemm_bt_k64<1, 0><<<dim3(32, 64), blk, 0, stream>>>(h2, w1T, b1, nullptr, ff1,
                                                        8192, 4096, 1024);
    gemm_bt_k64<0, 1><<<dim3(8, 64), blk, 0, stream>>>(ff1, w2T, b2, x2, out,
                                                       8192, 1024, 4096);
}

// Round 7
// 529.582 us; speedup vs baseline: 1.1983x; 1.0637x over previous
//
#include <hip/hip_runtime.h>
#include <hip/hip_bf16.h>
#include <stdint.h>

// Harness contract: reference is pure fp32 => all d_in are float*, d_out is
// float*. We convert to bf16 internally for MFMA, accumulate fp32.

typedef __attribute__((ext_vector_type(8))) short short8;   // 8 bf16 = 4 VGPRs (MFMA A/B frag)
typedef __attribute__((ext_vector_type(4))) short short4v;  // 4 bf16 = 8B
typedef __attribute__((ext_vector_type(4))) float floatx4;  // MFMA C/D frag

#define DEV static __device__ __forceinline__

DEV float b2f(short s) {
    unsigned u = ((unsigned)(unsigned short)s) << 16;
    return __uint_as_float(u);
}
DEV short f2b(float f) {  // round-to-nearest-even bf16
    unsigned u = __float_as_uint(f);
    u += 0x7fffu + ((u >> 16) & 1u);
    return (short)(u >> 16);
}

// async global->LDS, 16B per lane; HW writes lane i at wavebase + i*16
// (pass per-lane LDS ptr = base + lane*16 so source layout matches HW).
typedef const __attribute__((address_space(1))) unsigned gu32;
typedef __attribute__((address_space(3))) unsigned lu32;
DEV void g2l16(const void* g, void* l) {
    __builtin_amdgcn_global_load_lds((gu32*)(uintptr_t)g,
                                     (lu32*)(unsigned)(uintptr_t)l, 16, 0, 0);
}

// ---------------------------------------------------------------------------
// LayerNorm: y = gamma*(x-mean)/(std+eps)+beta, std = sqrt(sum((x-m)^2)/(n-1))
// fp32 in, bf16 out. one row (1024) per block of 256 threads
// ---------------------------------------------------------------------------
__global__ __launch_bounds__(256) void ln_kernel(const float* __restrict__ x,
                                                 const float* __restrict__ gamma,
                                                 const float* __restrict__ beta,
                                                 short* __restrict__ y) {
    int row = blockIdx.x;
    int t = threadIdx.x;
    float4 v = *(const float4*)(x + (size_t)row * 1024 + t * 4);
    float f[4] = {v.x, v.y, v.z, v.w};
    float s = 0.f, ss = 0.f;
#pragma unroll
    for (int i = 0; i < 4; i++) { s += f[i]; ss += f[i] * f[i]; }
#pragma unroll
    for (int off = 32; off; off >>= 1) { s += __shfl_xor(s, off); ss += __shfl_xor(ss, off); }
    __shared__ float rs[4], rss[4];
    int wid = t >> 6, lane = t & 63;
    if (lane == 0) { rs[wid] = s; rss[wid] = ss; }
    __syncthreads();
    s = rs[0] + rs[1] + rs[2] + rs[3];
    ss = rss[0] + rss[1] + rss[2] + rss[3];
    float mean = s * (1.0f / 1024.0f);
    float var = (ss - 1024.0f * mean * mean) * (1.0f / 1023.0f);
    var = fmaxf(var, 0.0f);
    float inv = 1.0f / (sqrtf(var) + 1e-5f);
    float4 g = *(const float4*)(gamma + t * 4);
    float4 bb = *(const float4*)(beta + t * 4);
    short4v o;
    o[0] = f2b(g.x * (f[0] - mean) * inv + bb.x);
    o[1] = f2b(g.y * (f[1] - mean) * inv + bb.y);
    o[2] = f2b(g.z * (f[2] - mean) * inv + bb.z);
    o[3] = f2b(g.w * (f[3] - mean) * inv + bb.w);
    *(short4v*)(y + (size_t)row * 1024 + t * 4) = o;
}

// ---------------------------------------------------------------------------
// Weight transpose + fp32->bf16: out[c*R + r] = bf16(in[r*C + c])
// ---------------------------------------------------------------------------
__global__ __launch_bounds__(256) void transpose_w(const float* __restrict__ in,
                                                   short* __restrict__ out,
                                                   int R, int C) {
    __shared__ short tile[32][33];
    int tx = threadIdx.x & 31, ty = threadIdx.x >> 5;
    int c0 = blockIdx.x * 32, r0 = blockIdx.y * 32;
#pragma unroll
    for (int i = 0; i < 4; i++)
        tile[ty + i * 8][tx] = f2b(in[(size_t)(r0 + ty + i * 8) * C + c0 + tx]);
    __syncthreads();
#pragma unroll
    for (int i = 0; i < 4; i++)
        out[(size_t)(c0 + ty + i * 8) * R + r0 + tx] = tile[tx][ty + i * 8];
}

// ---------------------------------------------------------------------------
// V^T prep: vt[bh][d][key] = qkv[b*2048+key][2048 + h*64 + d]  (bf16->bf16)
// grid: (64 key-tiles, 2 dim-tiles, 64 bh)
// ---------------------------------------------------------------------------
__global__ __launch_bounds__(256) void vtprep_kernel(const short* __restrict__ qkv,
                                                     short* __restrict__ vt) {
    __shared__ short tile[32][33];
    int tx = threadIdx.x & 31, ty = threadIdx.x >> 5;
    int bh = blockIdx.z, b = bh >> 4, h = bh & 15;
    int k0 = blockIdx.x * 32, d0 = blockIdx.y * 32;
#pragma unroll
    for (int i = 0; i < 4; i++)
        tile[ty + i * 8][tx] =
            qkv[(size_t)(b * 2048 + k0 + ty + i * 8) * 3072 + 2048 + h * 64 + d0 + tx];
    __syncthreads();
#pragma unroll
    for (int i = 0; i < 4; i++)
        vt[(size_t)bh * 131072 + (size_t)(d0 + ty + i * 8) * 2048 + k0 + tx] =
            tile[tx][ty + i * 8];
}

// ---------------------------------------------------------------------------
// GEMM (BK=64): C[M,N] = A[M,K](bf16) * Bt[N,K]^T(bf16) (+bias) (relu) (+res)
// Tile 128x128, 4 waves (2x2), 32 MFMA + 8 g2l16/lane per barrier pair.
// Used for the high-block-count GEMMs (QKV, FF1). LDS 32KB.
// Row stride 64 elems (128B); swizzle chunk c ^= row&7 -> measured 0 conflicts.
// ---------------------------------------------------------------------------
template <int RELU, int OUTF32>
__global__ __launch_bounds__(256) void gemm_bt_k64(const short* __restrict__ A,
                                                   const short* __restrict__ Bt,
                                                   const float* __restrict__ bias,
                                                   const float* __restrict__ res,
                                                   void* __restrict__ Cout,
                                                   int M, int N, int K) {
    __shared__ short lA[128 * 64];
    __shared__ short lB[128 * 64];
    int t = threadIdx.x;
    int bn = blockIdx.x, bm = blockIdx.y;
    int w = t >> 6, lane = t & 63, quad = lane >> 4, l15 = lane & 15;
    int wm = (w >> 1) * 64, wn = (w & 1) * 64;
    floatx4 acc[4][4] = {};
    const int nkt = K >> 6;
    const short* Ag[4]; const short* Bg[4];
    short* lAp[4]; short* lBp[4];
#pragma unroll
    for (int i = 0; i < 4; i++) {
        int S = i * 256 + t;
        int r = S >> 3, c = (S & 7) ^ (r & 7);
        Ag[i] = A + (size_t)(bm * 128 + r) * K + c * 8;
        Bg[i] = Bt + (size_t)(bn * 128 + r) * K + c * 8;
        lAp[i] = &lA[S * 8];
        lBp[i] = &lB[S * 8];
    }
    for (int kt = 0; kt < nkt; kt++) {
#pragma unroll
        for (int i = 0; i < 4; i++) {
            g2l16(Ag[i] + kt * 64, lAp[i]);
            g2l16(Bg[i] + kt * 64, lBp[i]);
        }
        __syncthreads();   // drains vmcnt(0)
        short8 af[2][4], bf[2][4];
#pragma unroll
        for (int kc = 0; kc < 2; kc++) {
#pragma unroll
            for (int mt = 0; mt < 4; mt++) {
                int row = wm + mt * 16 + l15;
                int c = (kc * 4 + quad) ^ (row & 7);
                af[kc][mt] = *(short8*)&lA[row * 64 + c * 8];
            }
#pragma unroll
            for (int nt = 0; nt < 4; nt++) {
                int row = wn + nt * 16 + l15;
                int c = (kc * 4 + quad) ^ (row & 7);
                bf[kc][nt] = *(short8*)&lB[row * 64 + c * 8];
            }
        }
#pragma unroll
        for (int kc = 0; kc < 2; kc++)
#pragma unroll
            for (int mt = 0; mt < 4; mt++)
#pragma unroll
                for (int nt = 0; nt < 4; nt++)
                    acc[mt][nt] = __builtin_amdgcn_mfma_f32_16x16x32_bf16(
                        af[kc][mt], bf[kc][nt], acc[mt][nt], 0, 0, 0);
        __syncthreads();
    }
#pragma unroll
    for (int mt = 0; mt < 4; mt++) {
#pragma unroll
        for (int nt = 0; nt < 4; nt++) {
            int col = bn * 128 + wn + nt * 16 + l15;
            float bv = bias ? bias[col] : 0.0f;
#pragma unroll
            for (int r = 0; r < 4; r++) {
                int row = bm * 128 + wm + mt * 16 + quad * 4 + r;
                float v = acc[mt][nt][r] + bv;
                if (RELU) v = fmaxf(v, 0.0f);
                if (res) v += res[(size_t)row * N + col];
                if (OUTF32)
                    ((float*)Cout)[(size_t)row * N + col] = v;
                else
                    ((short*)Cout)[(size_t)row * N + col] = f2b(v);
            }
        }
    }
}

// ---------------------------------------------------------------------------
// GEMM (BK=128 + XCD swizzle): for the grid-limited N=1024 GEMMs (Wout, FF2:
// 512 blocks = 2 blocks/CU). 64 MFMA + 16 g2l16/lane per barrier pair (halves
// the vmcnt(0) drain count vs BK=64); LDS 64KB -> still 2 blocks/CU.
// Block swizzle: HW dispatches linear id round-robin over 8 XCDs (xcd=id%8),
// so map each XCD's 64 co-resident blocks to an 8x8 (bm,bn) sub-grid:
// every A-tile & B-tile is then shared by 8 blocks through that XCD's L2
// (r6 FETCH showed 282MB vs 136MB min from zero cross-XCD tile reuse).
// Requires M=8192, N=1024, 1D grid of 512.
// ---------------------------------------------------------------------------
template <int RELU, int OUTF32>
__global__ __launch_bounds__(256) void gemm_bt_k128(const short* __restrict__ A,
                                                    const short* __restrict__ Bt,
                                                    const float* __restrict__ bias,
                                                    const float* __restrict__ res,
                                                    void* __restrict__ Cout,
                                                    int M, int N, int K) {
    __shared__ short lA[128 * 128];
    __shared__ short lB[128 * 128];
    int t = threadIdx.x;
    int lin = blockIdx.x;
    int xcd = lin & 7, slot = lin >> 3;
    int bm = xcd * 8 + (slot & 7);   // this XCD owns bm in [8*xcd, 8*xcd+8)
    int bn = slot >> 3;              // 0..7
    int w = t >> 6, lane = t & 63, quad = lane >> 4, l15 = lane & 15;
    int wm = (w >> 1) * 64, wn = (w & 1) * 64;
    floatx4 acc[4][4] = {};
    const int nkt = K >> 7;
    // 2048 16B chunks per buffer; 8 per lane. Row = 16 chunks (256B).
    const short* Ag[8]; const short* Bg[8];
    short* lAp[8]; short* lBp[8];
#pragma unroll
    for (int i = 0; i < 8; i++) {
        int S = i * 256 + t;
        int r = S >> 4, c = (S & 15) ^ (r & 15);
        Ag[i] = A + (size_t)(bm * 128 + r) * K + c * 8;
        Bg[i] = Bt + (size_t)(bn * 128 + r) * K + c * 8;
        lAp[i] = &lA[S * 8];
        lBp[i] = &lB[S * 8];
    }
    for (int kt = 0; kt < nkt; kt++) {
#pragma unroll
        for (int i = 0; i < 8; i++) {
            g2l16(Ag[i] + kt * 128, lAp[i]);
            g2l16(Bg[i] + kt * 128, lBp[i]);
        }
        __syncthreads();   // drains vmcnt(0)
#pragma unroll
        for (int kc = 0; kc < 4; kc++) {
            short8 af[4], bf[4];
#pragma unroll
            for (int mt = 0; mt < 4; mt++) {
                int row = wm + mt * 16 + l15;
                int c = (kc * 4 + quad) ^ (row & 15);
                af[mt] = *(short8*)&lA[row * 128 + c * 8];
            }
#pragma unroll
            for (int nt = 0; nt < 4; nt++) {
                int row = wn + nt * 16 + l15;
                int c = (kc * 4 + quad) ^ (row & 15);
                bf[nt] = *(short8*)&lB[row * 128 + c * 8];
            }
#pragma unroll
            for (int mt = 0; mt < 4; mt++)
#pragma unroll
                for (int nt = 0; nt < 4; nt++)
                    acc[mt][nt] = __builtin_amdgcn_mfma_f32_16x16x32_bf16(
                        af[mt], bf[nt], acc[mt][nt], 0, 0, 0);
        }
        __syncthreads();
    }
#pragma unroll
    for (int mt = 0; mt < 4; mt++) {
#pragma unroll
        for (int nt = 0; nt < 4; nt++) {
            int col = bn * 128 + wn + nt * 16 + l15;
            float bv = bias ? bias[col] : 0.0f;
#pragma unroll
            for (int r = 0; r < 4; r++) {
                int row = bm * 128 + wm + mt * 16 + quad * 4 + r;
                float v = acc[mt][nt][r] + bv;
                if (RELU) v = fmaxf(v, 0.0f);
                if (res) v += res[(size_t)row * N + col];
                if (OUTF32)
                    ((float*)Cout)[(size_t)row * N + col] = v;
                else
                    ((short*)Cout)[(size_t)row * N + col] = f2b(v);
            }
        }
    }
}

// ---------------------------------------------------------------------------
// Flash attention: grid (16 qtiles, 16 heads, 4 batch), block 256 = 4 waves
// each wave: 32 queries x 64 dims; K-tiles of 64 keys.
// No running max (|S/32| << 88). Q prescaled by 2^-5 (exact in bf16), so the
// softmax inner loop is just __expf + sum-add + v_perm truncation pack.
// lK rows key-permuted (row j holds key (j&15)*4+(j>>4)) -> P writes are one
// b64 per 4 contiguous k'. K/V staged via global_load_lds, XOR swizzle.
// ---------------------------------------------------------------------------
__global__ __launch_bounds__(256) void attn_kernel(const short* __restrict__ qkv,
                                                   const short* __restrict__ vt,
                                                   short* __restrict__ out) {
    __shared__ short lK[64 * 64];
    __shared__ short lV[64 * 64];
    __shared__ short lP[4 * 32 * 72];
    int t = threadIdx.x;
    int w = t >> 6, lane = t & 63, quad = lane >> 4, l15 = lane & 15;
    int qt = blockIdx.x, h = blockIdx.y, b = blockIdx.z;
    int qrow0 = b * 2048 + qt * 128 + w * 32;
    short* lPw = &lP[w * 32 * 72];

    // Q fragments, prescaled by SCALE = 2^-5 (exact in bf16)
    short8 qf[2][2];
#pragma unroll
    for (int mt = 0; mt < 2; mt++)
#pragma unroll
        for (int kc = 0; kc < 2; kc++) {
            short8 q = *(const short8*)(qkv + (size_t)(qrow0 + mt * 16 + l15) * 3072 +
                                        h * 64 + kc * 32 + quad * 8);
#pragma unroll
            for (int i = 0; i < 8; i++) q[i] = f2b(b2f(q[i]) * 0.03125f);
            qf[mt][kc] = q;
        }

    float l_s[2][4] = {};
    floatx4 o[2][4] = {};

    int S0 = w * 64 + lane, S1 = 256 + S0;
    int r0 = S0 >> 3, c0 = (S0 & 7) ^ (r0 & 7);
    int r1 = S1 >> 3, c1 = (S1 & 7) ^ (r1 & 7);
    int kr0 = (r0 & 15) * 4 + (r0 >> 4);
    int kr1 = (r1 & 15) * 4 + (r1 >> 4);
    const short* Kg0 = qkv + (size_t)(b * 2048 + kr0) * 3072 + 1024 + h * 64 + c0 * 8;
    const short* Kg1 = qkv + (size_t)(b * 2048 + kr1) * 3072 + 1024 + h * 64 + c1 * 8;
    const short* Vg0 = vt + (size_t)(b * 16 + h) * 131072 + (size_t)r0 * 2048 + c0 * 8;
    const short* Vg1 = vt + (size_t)(b * 16 + h) * 131072 + (size_t)r1 * 2048 + c1 * 8;
    short* lK0 = &lK[S0 * 8]; short* lK1 = &lK[S1 * 8];
    short* lV0 = &lV[S0 * 8]; short* lV1 = &lV[S1 * 8];

    for (int kt = 0; kt < 32; kt++) {
        __syncthreads();
        int key0 = kt * 64;
        g2l16(Kg0 + (size_t)key0 * 3072, lK0);
        g2l16(Kg1 + (size_t)key0 * 3072, lK1);
        g2l16(Vg0 + key0, lV0);
        g2l16(Vg1 + key0, lV1);
        __syncthreads();

        // S = (Q*2^-5) K^T   (col (nt,l15) is key k' = l15*4+nt)
        floatx4 s[2][4] = {};
#pragma unroll
        for (int kc = 0; kc < 2; kc++) {
            short8 kf[4];
#pragma unroll
            for (int nt = 0; nt < 4; nt++) {
                int row = nt * 16 + l15;
                int c = (kc * 4 + quad) ^ (row & 7);
                kf[nt] = *(short8*)&lK[row * 64 + c * 8];
            }
#pragma unroll
            for (int mt = 0; mt < 2; mt++)
#pragma unroll
                for (int nt = 0; nt < 4; nt++)
                    s[mt][nt] = __builtin_amdgcn_mfma_f32_16x16x32_bf16(
                        qf[mt][kc], kf[nt], s[mt][nt], 0, 0, 0);
        }

        // p = exp(S); lane-local partial row-sum; truncation-pack to bf16
#pragma unroll
        for (int mt = 0; mt < 2; mt++) {
#pragma unroll
            for (int r = 0; r < 4; r++) {
                float p0 = __expf(s[mt][0][r]);
                float p1 = __expf(s[mt][1][r]);
                float p2 = __expf(s[mt][2][r]);
                float p3 = __expf(s[mt][3][r]);
                l_s[mt][r] += (p0 + p1) + (p2 + p3);
                uint2 pk;
                pk.x = __builtin_amdgcn_perm(__float_as_uint(p1),
                                             __float_as_uint(p0), 0x07060302u);
                pk.y = __builtin_amdgcn_perm(__float_as_uint(p3),
                                             __float_as_uint(p2), 0x07060302u);
                *(uint2*)&lPw[(mt * 16 + quad * 4 + r) * 72 + l15 * 4] = pk;
            }
        }
        // lP is wave-private: no barrier needed

        // O += P V
#pragma unroll
        for (int kc = 0; kc < 2; kc++) {
            short8 pf[2], vf[4];
#pragma unroll
            for (int mt = 0; mt < 2; mt++)
                pf[mt] = *(short8*)&lPw[(mt * 16 + l15) * 72 + kc * 32 + quad * 8];
#pragma unroll
            for (int nt = 0; nt < 4; nt++) {
                int row = nt * 16 + l15;
                int c = (kc * 4 + quad) ^ (row & 7);
                vf[nt] = *(short8*)&lV[row * 64 + c * 8];
            }
#pragma unroll
            for (int mt = 0; mt < 2; mt++)
#pragma unroll
                for (int nt = 0; nt < 4; nt++)
                    o[mt][nt] = __builtin_amdgcn_mfma_f32_16x16x32_bf16(
                        pf[mt], vf[nt], o[mt][nt], 0, 0, 0);
        }
    }

#pragma unroll
    for (int mt = 0; mt < 2; mt++)
#pragma unroll
        for (int r = 0; r < 4; r++) {
            float v = l_s[mt][r];
            v += __shfl_xor(v, 1); v += __shfl_xor(v, 2);
            v += __shfl_xor(v, 4); v += __shfl_xor(v, 8);
            l_s[mt][r] = v;
        }

#pragma unroll
    for (int mt = 0; mt < 2; mt++)
#pragma unroll
        for (int nt = 0; nt < 4; nt++)
#pragma unroll
            for (int r = 0; r < 4; r++) {
                int row = qrow0 + mt * 16 + quad * 4 + r;
                int col = h * 64 + nt * 16 + l15;
                out[(size_t)row * 1024 + col] = f2b(o[mt][nt][r] / l_s[mt][r]);
            }
}

// ---------------------------------------------------------------------------
extern "C" void kernel_launch(void* const* d_in, const int* in_sizes, int n_in,
                              void* d_out, int out_size, void* d_ws, size_t ws_size,
                              hipStream_t stream) {
    const float* x      = (const float*)d_in[0];
    const float* w_qkv  = (const float*)d_in[1];
    const float* w_out  = (const float*)d_in[2];
    const float* b_out  = (const float*)d_in[3];
    const float* w1     = (const float*)d_in[4];
    const float* b1     = (const float*)d_in[5];
    const float* w2     = (const float*)d_in[6];
    const float* b2     = (const float*)d_in[7];
    const float* gamma1 = (const float*)d_in[8];
    const float* beta1  = (const float*)d_in[9];
    const float* gamma2 = (const float*)d_in[10];
    const float* beta2  = (const float*)d_in[11];
    float* out = (float*)d_out;

    // Workspace layout (byte offsets, 136MB high-water):
    //   0: wqkvT 6MB | 6: woutT 2MB | 8: w1T 8MB | 16: w2T 8MB
    //  24: h1 16MB (LN1 out -> attn out -> LN2 out)
    //  40: qkv 48MB + 88: vt 16MB  (both dead after attn; ff1 64MB spans both)
    // 104: x2 fp32 32MB (live to end)
    char* ws = (char*)d_ws;
    const size_t MB = 1024u * 1024u;
    short* wqkvT = (short*)(ws + 0 * MB);
    short* woutT = (short*)(ws + 6 * MB);
    short* w1T   = (short*)(ws + 8 * MB);
    short* w2T   = (short*)(ws + 16 * MB);
    short* h1    = (short*)(ws + 24 * MB);
    short* qkv   = (short*)(ws + 40 * MB);
    short* vt    = (short*)(ws + 88 * MB);
    short* ff1   = (short*)(ws + 40 * MB);
    float* x2    = (float*)(ws + 104 * MB);
    short* attn  = h1;   // h1 dead after QKV gemm
    short* h2    = h1;   // attn out dead after Wout gemm

    dim3 blk(256);
    transpose_w<<<dim3(96, 32), blk, 0, stream>>>(w_qkv, wqkvT, 1024, 3072);
    transpose_w<<<dim3(32, 32), blk, 0, stream>>>(w_out, woutT, 1024, 1024);
    transpose_w<<<dim3(128, 32), blk, 0, stream>>>(w1, w1T, 1024, 4096);
    transpose_w<<<dim3(32, 128), blk, 0, stream>>>(w2, w2T, 4096, 1024);

    ln_kernel<<<8192, blk, 0, stream>>>(x, gamma1, beta1, h1);
    gemm_bt_k64<0, 0><<<dim3(24, 64), blk, 0, stream>>>(h1, wqkvT, nullptr, nullptr,
                                                        qkv, 8192, 3072, 1024);
    vtprep_kernel<<<dim3(64, 2, 64), blk, 0, stream>>>(qkv, vt);
    attn_kernel<<<dim3(16, 16, 4), blk, 0, stream>>>(qkv, vt, attn);
    gemm_bt_k128<0, 1><<<dim3(512), blk, 0, stream>>>(attn, woutT, b_out, x, x2,
                                                      8192, 1024, 1024);
    ln_kernel<<<8192, blk, 0, stream>>>(x2, gamma2, beta2, h2);
    gemm_bt_k64<1, 0><<<dim3(32, 64), blk, 0, stream>>>(h2, w1T, b1, nullptr, ff1,
                                                        8192, 4096, 1024);
    gemm_bt_k128<0, 1><<<dim3(512), blk, 0, stream>>>(ff1, w2T, b2, x2, out,
                                                      8192, 1024, 4096);
}

// Round 8
// 502.434 us; speedup vs baseline: 1.2630x; 1.0540x over previous
//
#include <hip/hip_runtime.h>
#include <hip/hip_bf16.h>
#include <stdint.h>

// Harness contract: reference is pure fp32 => all d_in are float*, d_out is
// float*. We convert to bf16 internally for MFMA, accumulate fp32.

typedef __attribute__((ext_vector_type(8))) short short8;   // 8 bf16 = 4 VGPRs (MFMA A/B frag)
typedef __attribute__((ext_vector_type(4))) short short4v;  // 4 bf16 = 8B
typedef __attribute__((ext_vector_type(4))) float floatx4;  // MFMA C/D frag

#define DEV static __device__ __forceinline__

DEV float b2f(short s) {
    unsigned u = ((unsigned)(unsigned short)s) << 16;
    return __uint_as_float(u);
}
DEV short f2b(float f) {  // round-to-nearest-even bf16
    unsigned u = __float_as_uint(f);
    u += 0x7fffu + ((u >> 16) & 1u);
    return (short)(u >> 16);
}

// async global->LDS, 16B per lane; HW writes lane i at wavebase + i*16
// (pass per-lane LDS ptr = base + lane*16 so source layout matches HW).
typedef const __attribute__((address_space(1))) unsigned gu32;
typedef __attribute__((address_space(3))) unsigned lu32;
DEV void g2l16(const void* g, void* l) {
    __builtin_amdgcn_global_load_lds((gu32*)(uintptr_t)g,
                                     (lu32*)(unsigned)(uintptr_t)l, 16, 0, 0);
}

// ---------------------------------------------------------------------------
// LayerNorm: y = gamma*(x-mean)/(std+eps)+beta, std = sqrt(sum((x-m)^2)/(n-1))
// fp32 in, bf16 out. one row (1024) per block of 256 threads
// ---------------------------------------------------------------------------
__global__ __launch_bounds__(256) void ln_kernel(const float* __restrict__ x,
                                                 const float* __restrict__ gamma,
                                                 const float* __restrict__ beta,
                                                 short* __restrict__ y) {
    int row = blockIdx.x;
    int t = threadIdx.x;
    float4 v = *(const float4*)(x + (size_t)row * 1024 + t * 4);
    float f[4] = {v.x, v.y, v.z, v.w};
    float s = 0.f, ss = 0.f;
#pragma unroll
    for (int i = 0; i < 4; i++) { s += f[i]; ss += f[i] * f[i]; }
#pragma unroll
    for (int off = 32; off; off >>= 1) { s += __shfl_xor(s, off); ss += __shfl_xor(ss, off); }
    __shared__ float rs[4], rss[4];
    int wid = t >> 6, lane = t & 63;
    if (lane == 0) { rs[wid] = s; rss[wid] = ss; }
    __syncthreads();
    s = rs[0] + rs[1] + rs[2] + rs[3];
    ss = rss[0] + rss[1] + rss[2] + rss[3];
    float mean = s * (1.0f / 1024.0f);
    float var = (ss - 1024.0f * mean * mean) * (1.0f / 1023.0f);
    var = fmaxf(var, 0.0f);
    float inv = 1.0f / (sqrtf(var) + 1e-5f);
    float4 g = *(const float4*)(gamma + t * 4);
    float4 bb = *(const float4*)(beta + t * 4);
    short4v o;
    o[0] = f2b(g.x * (f[0] - mean) * inv + bb.x);
    o[1] = f2b(g.y * (f[1] - mean) * inv + bb.y);
    o[2] = f2b(g.z * (f[2] - mean) * inv + bb.z);
    o[3] = f2b(g.w * (f[3] - mean) * inv + bb.w);
    *(short4v*)(y + (size_t)row * 1024 + t * 4) = o;
}

// ---------------------------------------------------------------------------
// Weight transpose + fp32->bf16: out[c*R + r] = bf16(in[r*C + c])
// ---------------------------------------------------------------------------
__global__ __launch_bounds__(256) void transpose_w(const float* __restrict__ in,
                                                   short* __restrict__ out,
                                                   int R, int C) {
    __shared__ short tile[32][33];
    int tx = threadIdx.x & 31, ty = threadIdx.x >> 5;
    int c0 = blockIdx.x * 32, r0 = blockIdx.y * 32;
#pragma unroll
    for (int i = 0; i < 4; i++)
        tile[ty + i * 8][tx] = f2b(in[(size_t)(r0 + ty + i * 8) * C + c0 + tx]);
    __syncthreads();
#pragma unroll
    for (int i = 0; i < 4; i++)
        out[(size_t)(c0 + ty + i * 8) * R + r0 + tx] = tile[tx][ty + i * 8];
}

// ---------------------------------------------------------------------------
// V^T prep: vt[bh][d][key] = qkv[b*2048+key][2048 + h*64 + d]  (bf16->bf16)
// grid: (64 key-tiles, 2 dim-tiles, 64 bh)
// ---------------------------------------------------------------------------
__global__ __launch_bounds__(256) void vtprep_kernel(const short* __restrict__ qkv,
                                                     short* __restrict__ vt) {
    __shared__ short tile[32][33];
    int tx = threadIdx.x & 31, ty = threadIdx.x >> 5;
    int bh = blockIdx.z, b = bh >> 4, h = bh & 15;
    int k0 = blockIdx.x * 32, d0 = blockIdx.y * 32;
#pragma unroll
    for (int i = 0; i < 4; i++)
        tile[ty + i * 8][tx] =
            qkv[(size_t)(b * 2048 + k0 + ty + i * 8) * 3072 + 2048 + h * 64 + d0 + tx];
    __syncthreads();
#pragma unroll
    for (int i = 0; i < 4; i++)
        vt[(size_t)bh * 131072 + (size_t)(d0 + ty + i * 8) * 2048 + k0 + tx] =
            tile[tx][ty + i * 8];
}

// ---------------------------------------------------------------------------
// GEMM (BK=64): C[M,N] = A[M,K](bf16) * Bt[N,K]^T(bf16) (+bias) (relu) (+res)
// Tile 128x128, 4 waves (2x2), 32 MFMA + 8 g2l16/lane per barrier pair.
// Used for the high-block-count GEMMs (QKV, FF1). LDS 32KB.
// Row stride 64 elems (128B); swizzle chunk c ^= row&7 -> measured 0 conflicts.
// ---------------------------------------------------------------------------
template <int RELU, int OUTF32>
__global__ __launch_bounds__(256) void gemm_bt_k64(const short* __restrict__ A,
                                                   const short* __restrict__ Bt,
                                                   const float* __restrict__ bias,
                                                   const float* __restrict__ res,
                                                   void* __restrict__ Cout,
                                                   int M, int N, int K) {
    __shared__ short lA[128 * 64];
    __shared__ short lB[128 * 64];
    int t = threadIdx.x;
    int bn = blockIdx.x, bm = blockIdx.y;
    int w = t >> 6, lane = t & 63, quad = lane >> 4, l15 = lane & 15;
    int wm = (w >> 1) * 64, wn = (w & 1) * 64;
    floatx4 acc[4][4] = {};
    const int nkt = K >> 6;
    const short* Ag[4]; const short* Bg[4];
    short* lAp[4]; short* lBp[4];
#pragma unroll
    for (int i = 0; i < 4; i++) {
        int S = i * 256 + t;
        int r = S >> 3, c = (S & 7) ^ (r & 7);
        Ag[i] = A + (size_t)(bm * 128 + r) * K + c * 8;
        Bg[i] = Bt + (size_t)(bn * 128 + r) * K + c * 8;
        lAp[i] = &lA[S * 8];
        lBp[i] = &lB[S * 8];
    }
    for (int kt = 0; kt < nkt; kt++) {
#pragma unroll
        for (int i = 0; i < 4; i++) {
            g2l16(Ag[i] + kt * 64, lAp[i]);
            g2l16(Bg[i] + kt * 64, lBp[i]);
        }
        __syncthreads();   // drains vmcnt(0)
        short8 af[2][4], bf[2][4];
#pragma unroll
        for (int kc = 0; kc < 2; kc++) {
#pragma unroll
            for (int mt = 0; mt < 4; mt++) {
                int row = wm + mt * 16 + l15;
                int c = (kc * 4 + quad) ^ (row & 7);
                af[kc][mt] = *(short8*)&lA[row * 64 + c * 8];
            }
#pragma unroll
            for (int nt = 0; nt < 4; nt++) {
                int row = wn + nt * 16 + l15;
                int c = (kc * 4 + quad) ^ (row & 7);
                bf[kc][nt] = *(short8*)&lB[row * 64 + c * 8];
            }
        }
#pragma unroll
        for (int kc = 0; kc < 2; kc++)
#pragma unroll
            for (int mt = 0; mt < 4; mt++)
#pragma unroll
                for (int nt = 0; nt < 4; nt++)
                    acc[mt][nt] = __builtin_amdgcn_mfma_f32_16x16x32_bf16(
                        af[kc][mt], bf[kc][nt], acc[mt][nt], 0, 0, 0);
        __syncthreads();
    }
#pragma unroll
    for (int mt = 0; mt < 4; mt++) {
#pragma unroll
        for (int nt = 0; nt < 4; nt++) {
            int col = bn * 128 + wn + nt * 16 + l15;
            float bv = bias ? bias[col] : 0.0f;
#pragma unroll
            for (int r = 0; r < 4; r++) {
                int row = bm * 128 + wm + mt * 16 + quad * 4 + r;
                float v = acc[mt][nt][r] + bv;
                if (RELU) v = fmaxf(v, 0.0f);
                if (res) v += res[(size_t)row * N + col];
                if (OUTF32)
                    ((float*)Cout)[(size_t)row * N + col] = v;
                else
                    ((short*)Cout)[(size_t)row * N + col] = f2b(v);
            }
        }
    }
}

// ---------------------------------------------------------------------------
// GEMM (BK=128 + XCD swizzle): for the grid-limited N=1024 GEMMs (Wout, FF2:
// 512 blocks = 2 blocks/CU). 64 MFMA + 16 g2l16/lane per barrier pair; LDS
// 64KB -> still 2 blocks/CU. Each XCD's 64 co-resident blocks form an 8x8
// (bm,bn) sub-grid -> every tile shared by 8 blocks through that XCD's L2.
// ---------------------------------------------------------------------------
template <int RELU, int OUTF32>
__global__ __launch_bounds__(256) void gemm_bt_k128(const short* __restrict__ A,
                                                    const short* __restrict__ Bt,
                                                    const float* __restrict__ bias,
                                                    const float* __restrict__ res,
                                                    void* __restrict__ Cout,
                                                    int M, int N, int K) {
    __shared__ short lA[128 * 128];
    __shared__ short lB[128 * 128];
    int t = threadIdx.x;
    int lin = blockIdx.x;
    int xcd = lin & 7, slot = lin >> 3;
    int bm = xcd * 8 + (slot & 7);   // this XCD owns bm in [8*xcd, 8*xcd+8)
    int bn = slot >> 3;              // 0..7
    int w = t >> 6, lane = t & 63, quad = lane >> 4, l15 = lane & 15;
    int wm = (w >> 1) * 64, wn = (w & 1) * 64;
    floatx4 acc[4][4] = {};
    const int nkt = K >> 7;
    const short* Ag[8]; const short* Bg[8];
    short* lAp[8]; short* lBp[8];
#pragma unroll
    for (int i = 0; i < 8; i++) {
        int S = i * 256 + t;
        int r = S >> 4, c = (S & 15) ^ (r & 15);
        Ag[i] = A + (size_t)(bm * 128 + r) * K + c * 8;
        Bg[i] = Bt + (size_t)(bn * 128 + r) * K + c * 8;
        lAp[i] = &lA[S * 8];
        lBp[i] = &lB[S * 8];
    }
    for (int kt = 0; kt < nkt; kt++) {
#pragma unroll
        for (int i = 0; i < 8; i++) {
            g2l16(Ag[i] + kt * 128, lAp[i]);
            g2l16(Bg[i] + kt * 128, lBp[i]);
        }
        __syncthreads();   // drains vmcnt(0)
#pragma unroll
        for (int kc = 0; kc < 4; kc++) {
            short8 af[4], bf[4];
#pragma unroll
            for (int mt = 0; mt < 4; mt++) {
                int row = wm + mt * 16 + l15;
                int c = (kc * 4 + quad) ^ (row & 15);
                af[mt] = *(short8*)&lA[row * 128 + c * 8];
            }
#pragma unroll
            for (int nt = 0; nt < 4; nt++) {
                int row = wn + nt * 16 + l15;
                int c = (kc * 4 + quad) ^ (row & 15);
                bf[nt] = *(short8*)&lB[row * 128 + c * 8];
            }
#pragma unroll
            for (int mt = 0; mt < 4; mt++)
#pragma unroll
                for (int nt = 0; nt < 4; nt++)
                    acc[mt][nt] = __builtin_amdgcn_mfma_f32_16x16x32_bf16(
                        af[mt], bf[nt], acc[mt][nt], 0, 0, 0);
        }
        __syncthreads();
    }
#pragma unroll
    for (int mt = 0; mt < 4; mt++) {
#pragma unroll
        for (int nt = 0; nt < 4; nt++) {
            int col = bn * 128 + wn + nt * 16 + l15;
            float bv = bias ? bias[col] : 0.0f;
#pragma unroll
            for (int r = 0; r < 4; r++) {
                int row = bm * 128 + wm + mt * 16 + quad * 4 + r;
                float v = acc[mt][nt][r] + bv;
                if (RELU) v = fmaxf(v, 0.0f);
                if (res) v += res[(size_t)row * N + col];
                if (OUTF32)
                    ((float*)Cout)[(size_t)row * N + col] = v;
                else
                    ((short*)Cout)[(size_t)row * N + col] = f2b(v);
            }
        }
    }
}

// ---------------------------------------------------------------------------
// Flash attention v3: 1D grid 1024, block 256 = 4 waves, 32 q/wave.
// XCD swizzle: xcd=id&7 owns 8 (b,h) pairs x 16 qtiles -> each XCD's K/V
// working set = 8 x 512KB = 4MB = its L2 (r7 FETCH was 139MB vs 32MB unique).
// Double-buffered K/V: prefetch kt+1 AFTER the barrier, compute kt -> the
// vmcnt(0) drain at the next barrier waits on a load that aged one full
// compute phase. One barrier per iter.
// Base-2 softmax: Q prescaled by 2^-5*log2(e), p = exp2(S) via v_exp_f32.
// lK rows key-permuted (row j holds key (j&15)*4+(j>>4)) -> P writes are one
// b64 per 4 contiguous k'.
// ---------------------------------------------------------------------------
__global__ __launch_bounds__(256) void attn_kernel(const short* __restrict__ qkv,
                                                   const short* __restrict__ vt,
                                                   short* __restrict__ out) {
    __shared__ short lK[2][64 * 64];
    __shared__ short lV[2][64 * 64];
    __shared__ short lP[4 * 32 * 72];
    int t = threadIdx.x;
    int w = t >> 6, lane = t & 63, quad = lane >> 4, l15 = lane & 15;
    int lin = blockIdx.x;
    int xcd = lin & 7, slot = lin >> 3;
    int hb = xcd * 8 + (slot & 7);   // 64 (b,h) combos, 8 per XCD
    int qt = slot >> 3;              // 0..15
    int b = hb >> 4, h = hb & 15;
    int qrow0 = b * 2048 + qt * 128 + w * 32;
    short* lPw = &lP[w * 32 * 72];

    // Q fragments, prescaled by 2^-5 * log2(e) (RNE to bf16, err <= 2^-9 rel)
    short8 qf[2][2];
#pragma unroll
    for (int mt = 0; mt < 2; mt++)
#pragma unroll
        for (int kc = 0; kc < 2; kc++) {
            short8 q = *(const short8*)(qkv + (size_t)(qrow0 + mt * 16 + l15) * 3072 +
                                        h * 64 + kc * 32 + quad * 8);
#pragma unroll
            for (int i = 0; i < 8; i++) q[i] = f2b(b2f(q[i]) * 0.04508422f);
            qf[mt][kc] = q;
        }

    float l_s[2][4] = {};
    floatx4 o[2][4] = {};

    int S0 = w * 64 + lane, S1 = 256 + S0;
    int r0 = S0 >> 3, c0 = (S0 & 7) ^ (r0 & 7);
    int r1 = S1 >> 3, c1 = (S1 & 7) ^ (r1 & 7);
    int kr0 = (r0 & 15) * 4 + (r0 >> 4);
    int kr1 = (r1 & 15) * 4 + (r1 >> 4);
    const short* Kg0 = qkv + (size_t)(b * 2048 + kr0) * 3072 + 1024 + h * 64 + c0 * 8;
    const short* Kg1 = qkv + (size_t)(b * 2048 + kr1) * 3072 + 1024 + h * 64 + c1 * 8;
    const short* Vg0 = vt + (size_t)(b * 16 + h) * 131072 + (size_t)r0 * 2048 + c0 * 8;
    const short* Vg1 = vt + (size_t)(b * 16 + h) * 131072 + (size_t)r1 * 2048 + c1 * 8;

    auto stage = [&](int kt, int bufi) {
        int key0 = kt * 64;
        g2l16(Kg0 + (size_t)key0 * 3072, &lK[bufi][S0 * 8]);
        g2l16(Kg1 + (size_t)key0 * 3072, &lK[bufi][S1 * 8]);
        g2l16(Vg0 + key0, &lV[bufi][S0 * 8]);
        g2l16(Vg1 + key0, &lV[bufi][S1 * 8]);
    };

    stage(0, 0);
    for (int kt = 0; kt < 32; kt++) {
        int cur = kt & 1;
        __syncthreads();               // drains vmcnt: buf[cur] ready; WAR ok
        if (kt < 31) stage(kt + 1, cur ^ 1);   // lands during compute below

        // S = (Q*2^-5*log2e) K^T  (col (nt,l15) is key k' = l15*4+nt)
        floatx4 s[2][4] = {};
#pragma unroll
        for (int kc = 0; kc < 2; kc++) {
            short8 kf[4];
#pragma unroll
            for (int nt = 0; nt < 4; nt++) {
                int row = nt * 16 + l15;
                int c = (kc * 4 + quad) ^ (row & 7);
                kf[nt] = *(short8*)&lK[cur][row * 64 + c * 8];
            }
#pragma unroll
            for (int mt = 0; mt < 2; mt++)
#pragma unroll
                for (int nt = 0; nt < 4; nt++)
                    s[mt][nt] = __builtin_amdgcn_mfma_f32_16x16x32_bf16(
                        qf[mt][kc], kf[nt], s[mt][nt], 0, 0, 0);
        }

        // p = 2^S; lane-local partial row-sum; truncation-pack to bf16
#pragma unroll
        for (int mt = 0; mt < 2; mt++) {
#pragma unroll
            for (int r = 0; r < 4; r++) {
                float p0 = __builtin_amdgcn_exp2f(s[mt][0][r]);
                float p1 = __builtin_amdgcn_exp2f(s[mt][1][r]);
                float p2 = __builtin_amdgcn_exp2f(s[mt][2][r]);
                float p3 = __builtin_amdgcn_exp2f(s[mt][3][r]);
                l_s[mt][r] += (p0 + p1) + (p2 + p3);
                uint2 pk;
                pk.x = __builtin_amdgcn_perm(__float_as_uint(p1),
                                             __float_as_uint(p0), 0x07060302u);
                pk.y = __builtin_amdgcn_perm(__float_as_uint(p3),
                                             __float_as_uint(p2), 0x07060302u);
                *(uint2*)&lPw[(mt * 16 + quad * 4 + r) * 72 + l15 * 4] = pk;
            }
        }
        // lP is wave-private: no barrier needed

        // O += P V
#pragma unroll
        for (int kc = 0; kc < 2; kc++) {
            short8 pf[2], vf[4];
#pragma unroll
            for (int mt = 0; mt < 2; mt++)
                pf[mt] = *(short8*)&lPw[(mt * 16 + l15) * 72 + kc * 32 + quad * 8];
#pragma unroll
            for (int nt = 0; nt < 4; nt++) {
                int row = nt * 16 + l15;
                int c = (kc * 4 + quad) ^ (row & 7);
                vf[nt] = *(short8*)&lV[cur][row * 64 + c * 8];
            }
#pragma unroll
            for (int mt = 0; mt < 2; mt++)
#pragma unroll
                for (int nt = 0; nt < 4; nt++)
                    o[mt][nt] = __builtin_amdgcn_mfma_f32_16x16x32_bf16(
                        pf[mt], vf[nt], o[mt][nt], 0, 0, 0);
        }
    }

#pragma unroll
    for (int mt = 0; mt < 2; mt++)
#pragma unroll
        for (int r = 0; r < 4; r++) {
            float v = l_s[mt][r];
            v += __shfl_xor(v, 1); v += __shfl_xor(v, 2);
            v += __shfl_xor(v, 4); v += __shfl_xor(v, 8);
            l_s[mt][r] = v;
        }

#pragma unroll
    for (int mt = 0; mt < 2; mt++)
#pragma unroll
        for (int nt = 0; nt < 4; nt++)
#pragma unroll
            for (int r = 0; r < 4; r++) {
                int row = qrow0 + mt * 16 + quad * 4 + r;
                int col = h * 64 + nt * 16 + l15;
                out[(size_t)row * 1024 + col] = f2b(o[mt][nt][r] / l_s[mt][r]);
            }
}

// ---------------------------------------------------------------------------
extern "C" void kernel_launch(void* const* d_in, const int* in_sizes, int n_in,
                              void* d_out, int out_size, void* d_ws, size_t ws_size,
                              hipStream_t stream) {
    const float* x      = (const float*)d_in[0];
    const float* w_qkv  = (const float*)d_in[1];
    const float* w_out  = (const float*)d_in[2];
    const float* b_out  = (const float*)d_in[3];
    const float* w1     = (const float*)d_in[4];
    const float* b1     = (const float*)d_in[5];
    const float* w2     = (const float*)d_in[6];
    const float* b2     = (const float*)d_in[7];
    const float* gamma1 = (const float*)d_in[8];
    const float* beta1  = (const float*)d_in[9];
    const float* gamma2 = (const float*)d_in[10];
    const float* beta2  = (const float*)d_in[11];
    float* out = (float*)d_out;

    // Workspace layout (byte offsets, 136MB high-water):
    //   0: wqkvT 6MB | 6: woutT 2MB | 8: w1T 8MB | 16: w2T 8MB
    //  24: h1 16MB (LN1 out -> attn out -> LN2 out)
    //  40: qkv 48MB + 88: vt 16MB  (both dead after attn; ff1 64MB spans both)
    // 104: x2 fp32 32MB (live to end)
    char* ws = (char*)d_ws;
    const size_t MB = 1024u * 1024u;
    short* wqkvT = (short*)(ws + 0 * MB);
    short* woutT = (short*)(ws + 6 * MB);
    short* w1T   = (short*)(ws + 8 * MB);
    short* w2T   = (short*)(ws + 16 * MB);
    short* h1    = (short*)(ws + 24 * MB);
    short* qkv   = (short*)(ws + 40 * MB);
    short* vt    = (short*)(ws + 88 * MB);
    short* ff1   = (short*)(ws + 40 * MB);
    float* x2    = (float*)(ws + 104 * MB);
    short* attn  = h1;   // h1 dead after QKV gemm
    short* h2    = h1;   // attn out dead after Wout gemm

    dim3 blk(256);
    transpose_w<<<dim3(96, 32), blk, 0, stream>>>(w_qkv, wqkvT, 1024, 3072);
    transpose_w<<<dim3(32, 32), blk, 0, stream>>>(w_out, woutT, 1024, 1024);
    transpose_w<<<dim3(128, 32), blk, 0, stream>>>(w1, w1T, 1024, 4096);
    transpose_w<<<dim3(32, 128), blk, 0, stream>>>(w2, w2T, 4096, 1024);

    ln_kernel<<<8192, blk, 0, stream>>>(x, gamma1, beta1, h1);
    gemm_bt_k64<0, 0><<<dim3(24, 64), blk, 0, stream>>>(h1, wqkvT, nullptr, nullptr,
                                                        qkv, 8192, 3072, 1024);
    vtprep_kernel<<<dim3(64, 2, 64), blk, 0, stream>>>(qkv, vt);
    attn_kernel<<<dim3(1024), blk, 0, stream>>>(qkv, vt, attn);
    gemm_bt_k128<0, 1><<<dim3(512), blk, 0, stream>>>(attn, woutT, b_out, x, x2,
                                                      8192, 1024, 1024);
    ln_kernel<<<8192, blk, 0, stream>>>(x2, gamma2, beta2, h2);
    gemm_bt_k64<1, 0><<<dim3(32, 64), blk, 0, stream>>>(h2, w1T, b1, nullptr, ff1,
                                                        8192, 4096, 1024);
    gemm_bt_k128<0, 1><<<dim3(512), blk, 0, stream>>>(ff1, w2T, b2, x2, out,
                                                      8192, 1024, 4096);
}